// Round 7
// baseline (4161.177 us; speedup 1.0000x reference)
//
#include <hip/hip_runtime.h>
#include <stdint.h>

#define SEQ   2048
#define EMB   256
#define HHD   256      // per-direction hidden
#define GATES 1024     // 4*HHD
#define NTAGS 12
#define START 10
#define STOP  11
#define CCH   16       // CRF chunks
#define CLEN  128      // steps per chunk

typedef int v4i __attribute__((ext_vector_type(4)));

#define LOG2E 1.442695041f

__device__ __forceinline__ int sdot4(uint32_t a, uint32_t b, int c) {
#if __has_builtin(__builtin_amdgcn_sdot4)
  return __builtin_amdgcn_sdot4((int)a, (int)b, c, false);
#else
  int r = c;
#pragma unroll
  for (int i = 0; i < 4; i++) {
    int av = (int)(signed char)((a >> (8 * i)) & 255);
    int bv = (int)(signed char)((b >> (8 * i)) & 255);
    r += av * bv;
  }
  return r;
#endif
}

__device__ __forceinline__ float fexp2(float x) {
#if __has_builtin(__builtin_amdgcn_exp2f)
  return __builtin_amdgcn_exp2f(x);
#else
  return exp2f(x);
#endif
}

__device__ __forceinline__ v4i mfma_i8_16x16x64(v4i a, v4i b, v4i c) {
#if __has_builtin(__builtin_amdgcn_mfma_i32_16x16x64_i8)
  return __builtin_amdgcn_mfma_i32_16x16x64_i8(a, b, c, 0, 0, 0);
#else
  return c;  // gfx950 always has it; fallback only to keep compile alive
#endif
}

// DPP quad_perm lane swaps (stay on VALU pipe, no LDS)
__device__ __forceinline__ int dpp_xor1(int x) {   // lanes q <-> q^1 : [1,0,3,2]
  return __builtin_amdgcn_update_dpp(0, x, 0xB1, 0xF, 0xF, true);
}
__device__ __forceinline__ int dpp_xor2(int x) {   // lanes q <-> q^2 : [2,3,0,1]
  return __builtin_amdgcn_update_dpp(0, x, 0x4E, 0xF, 0xF, true);
}
__device__ __forceinline__ float dpp_xor2_f(float x) {
  int r = __builtin_amdgcn_update_dpp(0, __float_as_int(x), 0x4E, 0xF, 0xF, true);
  return __int_as_float(r);
}

// ---------------- 1. Whh fp32 -> int8 rows + per-row scale + exact Whh@h0 ----------
// one wave per row; lane k holds 4 consecutive weights -> 1 packed dword.
// h0c[row] = fp32-exact dot(Whh[row], h0) -- folded into pre[t0] so the LSTM
// h-seed is zero (removes all step-0 scale special-casing from the hot loop).
__global__ __launch_bounds__(256) void k_quant(const float* __restrict__ whh_f,
                                               const float* __restrict__ whh_b,
                                               const float* __restrict__ h0,
                                               uint32_t* __restrict__ q4,
                                               float* __restrict__ scales,
                                               float* __restrict__ h0c) {
  const int row  = (blockIdx.x * 256 + threadIdx.x) >> 6;  // 0..2047
  const int lane = threadIdx.x & 63;
  const int d = row >> 10, r = row & 1023;
  const float4 w = *(const float4*)((d ? whh_b : whh_f) + (long)r * HHD + lane * 4);

  const float4 hh = *(const float4*)(h0 + d * HHD + lane * 4);
  float dp = w.x * hh.x + w.y * hh.y + w.z * hh.z + w.w * hh.w;
#pragma unroll
  for (int off = 32; off; off >>= 1) dp += __shfl_xor(dp, off, 64);

  float m = fmaxf(fmaxf(fabsf(w.x), fabsf(w.y)), fmaxf(fabsf(w.z), fabsf(w.w)));
#pragma unroll
  for (int off = 32; off; off >>= 1) m = fmaxf(m, __shfl_xor(m, off, 64));
  m = fmaxf(m, 1e-20f);
  const float inv = 127.f / m;
  int a = (int)rintf(w.x * inv), b = (int)rintf(w.y * inv);
  int c = (int)rintf(w.z * inv), e = (int)rintf(w.w * inv);
  q4[row * 64 + lane] = (uint32_t)(a & 255) | ((uint32_t)(b & 255) << 8) |
                        ((uint32_t)(c & 255) << 16) | ((uint32_t)(e & 255) << 24);
  if (lane == 0) { scales[row] = m / 127.f; h0c[row] = dp; }
}

// ---------------- 2. input projection, gate-interleaved, exp2-premultiplied ---------
// pre layout: [dir][t][unit][{i,f,g,o}] (float4/unit), value = -fac[G]*(true pre),
// fac = 2*log2e for g-gate (tanh), log2e otherwise -> k_lstm consumers feed exp2
// directly with zero extra muls.  pre[t0] additionally absorbs the exact Whh@h0.
__global__ __launch_bounds__(256) void k_proj(const int* __restrict__ sentence,
                                              const float* __restrict__ embed,
                                              const float* __restrict__ Wih_f,
                                              const float* __restrict__ bih_f,
                                              const float* __restrict__ bhh_f,
                                              const float* __restrict__ Wih_b,
                                              const float* __restrict__ bih_b,
                                              const float* __restrict__ bhh_b,
                                              const float* __restrict__ h0c,
                                              float* __restrict__ pre) {
  const int dir = blockIdx.y;
  const int t0  = blockIdx.x * 8;
  const float* Wih = dir ? Wih_b : Wih_f;
  const float* bih = dir ? bih_b : bih_f;
  const float* bhh = dir ? bhh_b : bhh_f;

  __shared__ float xs[8][256];
  const int tid = threadIdx.x;
#pragma unroll
  for (int i = 0; i < 8; i++) {
    int s = sentence[t0 + i];
    xs[i][tid] = embed[(long)s * EMB + tid];
  }
  __syncthreads();

  const int r0 = tid * 4;
  float acc[4][8];
#pragma unroll
  for (int j = 0; j < 4; j++)
#pragma unroll
    for (int t = 0; t < 8; t++) acc[j][t] = 0.f;

  const float4* W4 = (const float4*)Wih;
  for (int kq = 0; kq < 64; kq++) {
    float4 w[4];
#pragma unroll
    for (int j = 0; j < 4; j++) w[j] = W4[(r0 + j) * 64 + kq];
#pragma unroll
    for (int t = 0; t < 8; t++) {
      float4 xv = ((const float4*)xs[t])[kq];
#pragma unroll
      for (int j = 0; j < 4; j++)
        acc[j][t] += w[j].x * xv.x + w[j].y * xv.y + w[j].z * xv.z + w[j].w * xv.w;
    }
  }
  const int t0d = dir ? (SEQ - 1) : 0;
#pragma unroll
  for (int j = 0; j < 4; j++) {
    const int row = r0 + j;
    const int G  = row >> 8;             // 0:i 1:f 2:g 3:o (PyTorch order)
    const int uu = row & 255;            // unit
    const float negfac = (G == 2) ? (-2.f * LOG2E) : (-LOG2E);
    const float bsum = bih[row] + bhh[row];
    const float c0a  = h0c[dir * GATES + row];
#pragma unroll
    for (int t = 0; t < 8; t++) {
      float v = acc[j][t] + bsum;
      if (t0 + t == t0d) v += c0a;       // exact fp32 Whh@h0 at the first step
      pre[(((long)(dir * SEQ + t0 + t)) * HHD + uu) * 4 + G] = v * negfac;
    }
  }
}

// ---------------- 3. sequential LSTM: role-per-wave hybrid, ONE barrier/step --------
// 8 waves/block, 1 block/dir.  Per SIMD: one sdot wave + one mfma wave.
//   waves 0..3 (sdot role, units 0..127): R1 K-split-quad + DPP butterfly,
//     128 v_dot4/lane, self-consuming (VALU pipe).
//   waves 4..7 (mfma role, units 128..255): wave m owns 32 units = 2 tiles x
//     4 gates x 4 K-chunks = 32 mfma_i32_16x16x64_i8 (matrix pipe).  B = h
//     K-chunk replicated over all 16 cols -> ALL columns of D are identical,
//     so every lane already holds rows lg*4+reg of its tile in acc registers.
//     NO LDS transpose (R6's 500cy tail): lane (col,lg) owns unit
//     ub + (col>>3)*16 + lg*4 + (col&3), active cols {0..3, 8..11} (32 lanes,
//     1 unit each); gate dots extracted with compile-time cndmask ternaries;
//     activation runs in parallel across lanes.
// Activations in exp2 domain (pre & scales premultiplied by -log2e*fac);
// h zero-seeded (Whh@h0 folded into pre[t0]).  One lgkm-barrier per step.
__global__ __launch_bounds__(512, 2) void k_lstm(const uint32_t* __restrict__ q4,
                                                 const float* __restrict__ scales,
                                                 const float* __restrict__ pre,
                                                 const float* __restrict__ c0,
                                                 float* __restrict__ hs) {
  const int dir  = blockIdx.x;
  const int L    = threadIdx.x;
  const int w    = L >> 6;             // wave 0..7
  const int lane = L & 63;
  const long base = (long)dir * GATES;

  __shared__ __align__(16) uint8_t hbuf[2][256];

  const float k1 = -LOG2E / 127.f;
  const float k2 = -2.f * LOG2E / 127.f;

  if (L < 256) hbuf[0][L] = 0;         // zero seed (h0 folded into pre[t0])
  __syncthreads();

  const int t0 = dir ? (SEQ - 1) : 0;
  const long pstep = dir ? -(long)(HHD * 4) : (long)(HHD * 4);
  const long hstep = dir ? -(long)HHD : (long)HHD;
  const uint4* qq = (const uint4*)q4;

  if (w < 4) {
    // ================= sdot role (units 0..127) — R1 structure =================
    const int q    = L & 3;
    const int g    = L >> 2;           // 0..63
    const int p    = q & 1;
    const int half = q >> 1;
    const int u    = 2 * g + p;        // 0..127

    uint4 wa[4][4], wb[4][4];
#pragma unroll
    for (int j = 0; j < 4; j++) {
      const int qj = q ^ j;
      const int rA = (2 * (qj >> 1)) * 256 + 2 * g + (qj & 1);
      const int rB = rA + 256;
#pragma unroll
      for (int k = 0; k < 4; k++) {
        wa[j][k] = qq[(base + rA) * 16 + 4 * q + k];   // own K-quarter q
        wb[j][k] = qq[(base + rB) * 16 + 4 * q + k];
      }
    }
    const int rown = (2 * half) * 256 + u;             // own A row (gate 0|2)
    const float scvA = (half ? k2 : k1) * scales[base + rown];
    const float scvB = k1 * scales[base + rown + 256];
    float c_st = c0[dir * HHD + u];

    const float* pp = pre + ((long)(dir * SEQ + t0) * HHD + u) * 4 + 2 * half;
    float* hp       = hs + (long)dir * SEQ * HHD + (long)t0 * HHD + u;
    const float gmul = half ? 2.f : 1.f;
    const int write_h = ((L & 2) == 0);

    for (int s = 0; s < SEQ; s++) {
      const float2 pr = *(const float2*)pp;

      const uint4* hq4 = (const uint4*)(hbuf[s & 1] + (q << 6));
      const uint4 h0v = hq4[0], h1v = hq4[1], h2v = hq4[2], h3v = hq4[3];

      int pa0 = 0, pa1 = 0, pa2 = 0, pa3 = 0;
      int pb0 = 0, pb1 = 0, pb2 = 0, pb3 = 0;
#pragma unroll
      for (int k = 0; k < 4; k++) {
        const uint4 hk = (k == 0) ? h0v : (k == 1) ? h1v : (k == 2) ? h2v : h3v;
        pa0 = sdot4(wa[0][k].x, hk.x, pa0); pa0 = sdot4(wa[0][k].y, hk.y, pa0);
        pa0 = sdot4(wa[0][k].z, hk.z, pa0); pa0 = sdot4(wa[0][k].w, hk.w, pa0);
        pa1 = sdot4(wa[1][k].x, hk.x, pa1); pa1 = sdot4(wa[1][k].y, hk.y, pa1);
        pa1 = sdot4(wa[1][k].z, hk.z, pa1); pa1 = sdot4(wa[1][k].w, hk.w, pa1);
        pa2 = sdot4(wa[2][k].x, hk.x, pa2); pa2 = sdot4(wa[2][k].y, hk.y, pa2);
        pa2 = sdot4(wa[2][k].z, hk.z, pa2); pa2 = sdot4(wa[2][k].w, hk.w, pa2);
        pa3 = sdot4(wa[3][k].x, hk.x, pa3); pa3 = sdot4(wa[3][k].y, hk.y, pa3);
        pa3 = sdot4(wa[3][k].z, hk.z, pa3); pa3 = sdot4(wa[3][k].w, hk.w, pa3);
        pb0 = sdot4(wb[0][k].x, hk.x, pb0); pb0 = sdot4(wb[0][k].y, hk.y, pb0);
        pb0 = sdot4(wb[0][k].z, hk.z, pb0); pb0 = sdot4(wb[0][k].w, hk.w, pb0);
        pb1 = sdot4(wb[1][k].x, hk.x, pb1); pb1 = sdot4(wb[1][k].y, hk.y, pb1);
        pb1 = sdot4(wb[1][k].z, hk.z, pb1); pb1 = sdot4(wb[1][k].w, hk.w, pb1);
        pb2 = sdot4(wb[2][k].x, hk.x, pb2); pb2 = sdot4(wb[2][k].y, hk.y, pb2);
        pb2 = sdot4(wb[2][k].z, hk.z, pb2); pb2 = sdot4(wb[2][k].w, hk.w, pb2);
        pb3 = sdot4(wb[3][k].x, hk.x, pb3); pb3 = sdot4(wb[3][k].y, hk.y, pb3);
        pb3 = sdot4(wb[3][k].z, hk.z, pb3); pb3 = sdot4(wb[3][k].w, hk.w, pb3);
      }
      const int tA = pa0 + dpp_xor1(pa1);
      const int tA2 = pa2 + dpp_xor1(pa3);
      const int sumA = tA + dpp_xor2(tA2);
      const int tB = pb0 + dpp_xor1(pb1);
      const int tB2 = pb2 + dpp_xor1(pb3);
      const int sumB = tB + dpp_xor2(tB2);

      const float gA2 = fmaf(scvA, (float)sumA, pr.x);  // exp2-domain
      const float gB2 = fmaf(scvB, (float)sumB, pr.y);
      const float e0 = __builtin_amdgcn_rcpf(1.f + fexp2(gA2));
      const float v0 = fmaf(e0, gmul, -(gmul - 1.f));   // i (half0) | tanh=g (half1)
      const float v1 = __builtin_amdgcn_rcpf(1.f + fexp2(gB2));  // f | o
      const float p0 = dpp_xor2_f(v0);
      const float p1 = dpp_xor2_f(v1);
      const float iv = half ? p0 : v0;
      const float fv = half ? p1 : v1;
      const float gv = half ? v0 : p0;
      const float ov = half ? v1 : p1;

      c_st = fmaf(fv, c_st, iv * gv);
      const float th = fmaf(2.f, __builtin_amdgcn_rcpf(1.f + fexp2(c_st * (-2.f * LOG2E))), -1.f);
      const float hv = ov * th;

      if (write_h) {
        *hp = hv;
        hbuf[(s + 1) & 1][u] = (uint8_t)(int)rintf(hv * 127.f);  // |hv|<1
      }
      pp += pstep;
      hp += hstep;
      asm volatile("s_waitcnt lgkmcnt(0)\n\ts_barrier" ::: "memory");
    }
  } else {
    // ================= mfma role (units 128..255), direct-extract =================
    const int m   = w - 4;             // 0..3
    const int lg  = lane >> 4;         // 0..3
    const int col = lane & 15;
    const int ub  = 128 + 32 * m;      // this wave's unit base

    // A fragments: row = G*256 + ub + t*16 + col ; k-window (kc*4+lg)*16 bytes
    v4i A[4][2][4];
#pragma unroll
    for (int G = 0; G < 4; G++)
#pragma unroll
      for (int t = 0; t < 2; t++) {
        const int row = G * 256 + ub + t * 16 + col;
#pragma unroll
        for (int kc = 0; kc < 4; kc++) {
          const uint4 a = qq[(base + row) * 16 + kc * 4 + lg];
          A[G][t][kc] = (v4i){(int)a.x, (int)a.y, (int)a.z, (int)a.w};
        }
      }

    // lane -> unit assignment (cols replicated in D, so acc already holds rows
    // lg*4+reg): t = col>>3, reg = col&3; active cols {0..3, 8..11}
    const int t_sel = col >> 3;
    const int reg   = col & 3;
    const bool act_lane = ((col & 4) == 0);
    const int uu = ub + t_sel * 16 + lg * 4 + reg;   // this lane's unit

    const float scv0 = k1 * scales[base + 0 * 256 + uu];
    const float scv1 = k1 * scales[base + 1 * 256 + uu];
    const float scv2 = k2 * scales[base + 2 * 256 + uu];
    const float scv3 = k1 * scales[base + 3 * 256 + uu];
    float c_st = c0[dir * HHD + uu];

    const float* pp = pre + ((long)(dir * SEQ + t0) * HHD + uu) * 4;
    float* hp       = hs + (long)dir * SEQ * HHD + (long)t0 * HHD + uu;

    for (int s = 0; s < SEQ; s++) {
      const float4 pc = *(const float4*)pp;

      const uint8_t* hb = hbuf[s & 1];
      v4i B[4];
#pragma unroll
      for (int kc = 0; kc < 4; kc++) {
        const uint4 hf = *(const uint4*)(hb + kc * 64 + lg * 16);
        B[kc] = (v4i){(int)hf.x, (int)hf.y, (int)hf.z, (int)hf.w};
      }
      v4i acc[4][2];
#pragma unroll
      for (int G = 0; G < 4; G++)
#pragma unroll
        for (int t = 0; t < 2; t++) {
          v4i a = (v4i){0, 0, 0, 0};
#pragma unroll
          for (int kc = 0; kc < 4; kc++) a = mfma_i8_16x16x64(A[G][t][kc], B[kc], a);
          acc[G][t] = a;
        }

      // extract this lane's unit: tile by t_sel (4 cndmask), component by reg
      // (3 cndmask) -- all compile-time-unrolled register selects, no scratch
      int d[4];
#pragma unroll
      for (int G = 0; G < 4; G++) {
        const v4i a = t_sel ? acc[G][1] : acc[G][0];
        d[G] = (reg == 0) ? a.x : (reg == 1) ? a.y : (reg == 2) ? a.z : a.w;
      }

      const float ai = fmaf(scv0, (float)d[0], pc.x);
      const float af = fmaf(scv1, (float)d[1], pc.y);
      const float ag = fmaf(scv2, (float)d[2], pc.z);
      const float ao = fmaf(scv3, (float)d[3], pc.w);
      const float iv = __builtin_amdgcn_rcpf(1.f + fexp2(ai));
      const float fv = __builtin_amdgcn_rcpf(1.f + fexp2(af));
      const float gv = fmaf(2.f, __builtin_amdgcn_rcpf(1.f + fexp2(ag)), -1.f);
      const float ov = __builtin_amdgcn_rcpf(1.f + fexp2(ao));
      c_st = fmaf(fv, c_st, iv * gv);
      const float th = fmaf(2.f, __builtin_amdgcn_rcpf(1.f + fexp2(c_st * (-2.f * LOG2E))), -1.f);
      const float hv = ov * th;

      if (act_lane) {
        *hp = hv;
        hbuf[(s + 1) & 1][uu] = (uint8_t)(int)rintf(hv * 127.f);  // |hv|<1
      }
      pp += pstep;
      hp += hstep;
      asm volatile("s_waitcnt lgkmcnt(0)\n\ts_barrier" ::: "memory");
    }
  }
}

// ---------------- 4. feats[t][n] = b_out[n] + W_out[n] . [hf[t]; hb[t]] --------------
__global__ __launch_bounds__(192) void k_feats(const float* __restrict__ hs,
                                               const float* __restrict__ W_out,
                                               const float* __restrict__ b_out,
                                               float* __restrict__ feats) {
  __shared__ float Wl[12 * 520];
  const int tid = threadIdx.x;
  for (int i = tid; i < 12 * 512; i += 192) Wl[(i / 512) * 520 + (i % 512)] = W_out[i];
  __syncthreads();

  const int tl = tid / 12, n = tid % 12;
  const int t = blockIdx.x * 16 + tl;
  const float4* hf4 = (const float4*)(hs + (long)t * HHD);
  const float4* hb4 = (const float4*)(hs + (long)SEQ * HHD + (long)t * HHD);
  const float4* Wa  = (const float4*)&Wl[n * 520];
  const float4* Wb  = (const float4*)&Wl[n * 520 + 256];

  float acc = b_out[n];
#pragma unroll 8
  for (int j = 0; j < 64; j++) {
    float4 w = Wa[j], h = hf4[j];
    acc += w.x * h.x + w.y * h.y + w.z * h.z + w.w * h.w;
  }
#pragma unroll 8
  for (int j = 0; j < 64; j++) {
    float4 w = Wb[j], h = hb4[j];
    acc += w.x * h.x + w.y * h.y + w.z * h.z + w.w * h.w;
  }
  feats[t * NTAGS + n] = acc;
}

// ---------------- 5a. CRF chunk: fold 128 steps into a 12x12 log-semiring matrix -----
__global__ __launch_bounds__(192) void k_crf_chunk(const float* __restrict__ feats,
                                                   const float* __restrict__ trans,
                                                   float* __restrict__ Pc) {
  const int ch  = blockIdx.x;
  const int tid = threadIdx.x;
  const int n   = tid & 15;
  const int p   = tid >> 4;                // 0..11
  const int nn  = (n < 12) ? n : 11;

  __shared__ float fe[CLEN * NTAGS];
  for (int i = tid; i < CLEN * NTAGS; i += 192) fe[i] = feats[ch * CLEN * NTAGS + i];
  __syncthreads();

  float trn[12];
#pragma unroll
  for (int j = 0; j < 12; j++) trn[j] = trans[nn * 12 + j];

  float Mv = trans[nn * 12 + p] + fe[nn];  // A_{t0}[n,p]
  for (int t = 1; t < CLEN; t++) {
    float x[12], m = -1e30f;
#pragma unroll
    for (int j = 0; j < 12; j++) {
      x[j] = trn[j] + __shfl(Mv, (tid & 48) | j, 64);
      m = fmaxf(m, x[j]);
    }
    float ss = 0.f;
#pragma unroll
    for (int j = 0; j < 12; j++) ss += __expf(x[j] - m);
    Mv = fe[t * NTAGS + nn] + m + __logf(ss);
  }
  if (n < 12) Pc[ch * 144 + n * 12 + p] = Mv;
}

// ---------------- 5b. combine chunk matrices + stop + gold score ---------------------
__global__ __launch_bounds__(128) void k_crf_final(const float* __restrict__ Pc,
                                                   const float* __restrict__ feats,
                                                   const int* __restrict__ tags,
                                                   const float* __restrict__ trans,
                                                   float* __restrict__ out) {
  __shared__ float Pl[CCH * 144];
  __shared__ float res[2];
  const int tid = threadIdx.x;
  for (int i = tid; i < CCH * 144; i += 128) Pl[i] = Pc[i];
  __syncthreads();

  if (tid < 64) {
    const int n  = tid;
    const int nn = (n < 12) ? n : 11;
    float fv = (n == START) ? 0.f : -10000.f;
    for (int c = 0; c < CCH; c++) {
      float x[12], m = -1e30f;
#pragma unroll
      for (int j = 0; j < 12; j++) {
        x[j] = Pl[c * 144 + nn * 12 + j] + __shfl(fv, j, 64);
        m = fmaxf(m, x[j]);
      }
      float ss = 0.f;
#pragma unroll
      for (int j = 0; j < 12; j++) ss += __expf(x[j] - m);
      fv = m + __logf(ss);
    }
    const float v = fv + trans[STOP * 12 + nn];
    float xs[12], m = -1e30f;
#pragma unroll
    for (int j = 0; j < 12; j++) {
      xs[j] = __shfl(v, j, 64);
      m = fmaxf(m, xs[j]);
    }
    float ss = 0.f;
#pragma unroll
    for (int j = 0; j < 12; j++) ss += __expf(xs[j] - m);
    if (tid == 0) res[0] = m + __logf(ss);
  } else {
    const int i = tid - 64;
    float gp = 0.f;
    for (int b = 0; b < 32; b++) {
      int t  = b * 64 + i;
      int tg = tags[t];
      int pv = (t == 0) ? START : tags[t - 1];
      gp += trans[tg * 12 + pv] + feats[t * NTAGS + tg];
    }
#pragma unroll
    for (int off = 32; off; off >>= 1) gp += __shfl_xor(gp, off, 64);
    if (i == 0) res[1] = gp + trans[STOP * 12 + tags[SEQ - 1]];
  }
  __syncthreads();
  if (tid == 0) out[0] = res[0] - res[1];
}

// -------------------------------------------------------------------------------------
extern "C" void kernel_launch(void* const* d_in, const int* in_sizes, int n_in,
                              void* d_out, int out_size, void* d_ws, size_t ws_size,
                              hipStream_t stream) {
  const int*   sentence = (const int*)  d_in[0];
  const int*   tags     = (const int*)  d_in[1];
  const float* embed    = (const float*)d_in[2];
  const float* Wih_f    = (const float*)d_in[3];
  const float* Whh_f    = (const float*)d_in[4];
  const float* bih_f    = (const float*)d_in[5];
  const float* bhh_f    = (const float*)d_in[6];
  const float* Wih_b    = (const float*)d_in[7];
  const float* Whh_b    = (const float*)d_in[8];
  const float* bih_b    = (const float*)d_in[9];
  const float* bhh_b    = (const float*)d_in[10];
  const float* W_out    = (const float*)d_in[11];
  const float* b_out    = (const float*)d_in[12];
  const float* h0       = (const float*)d_in[13];
  const float* c0       = (const float*)d_in[14];
  const float* trans    = (const float*)d_in[15];
  float* out = (float*)d_out;

  char* ws = (char*)d_ws;
  uint32_t* q4    = (uint32_t*)ws;                          // 512 KB
  float*    scales= (float*)(ws + (512l << 10));            // 8 KB
  float*    h0c   = (float*)(ws + (520l << 10));            // 8 KB : Whh@h0 per row
  float*    pre   = (float*)(ws + (1l  << 20));             // 16 MB : pre[2][2048][256][4]
  float*    hs    = (float*)(ws + (17l << 20));             // 4 MB  : hs[2][2048][256]
  float*    feats = (float*)(ws + (21l << 20));             // 96 KB : feats[2048][12]
  float*    Pc    = (float*)(ws + (21l << 20) + (128l<<10));// 9 KB  : Pc[16][12][12]

  k_quant<<<512, 256, 0, stream>>>(Whh_f, Whh_b, h0, q4, scales, h0c);
  k_proj<<<dim3(256, 2), 256, 0, stream>>>(sentence, embed, Wih_f, bih_f, bhh_f,
                                           Wih_b, bih_b, bhh_b, h0c, pre);
  k_lstm<<<2, 512, 0, stream>>>(q4, scales, pre, c0, hs);
  k_feats<<<128, 192, 0, stream>>>(hs, W_out, b_out, feats);
  k_crf_chunk<<<CCH, 192, 0, stream>>>(feats, trans, Pc);
  k_crf_final<<<1, 128, 0, stream>>>(Pc, feats, tags, trans, out);
}

// Round 8
// 1890.751 us; speedup vs baseline: 2.2008x; 2.2008x over previous
//
#include <hip/hip_runtime.h>
#include <hip/hip_bf16.h>
#include <stdint.h>

#define SEQ   2048
#define EMB   256
#define HHD   256      // per-direction hidden
#define GATES 1024     // 4*HHD
#define NTAGS 12
#define START 10
#define STOP  11
#define CCH   16       // CRF chunks
#define CLEN  128      // steps per chunk

__device__ __forceinline__ int sdot4(uint32_t a, uint32_t b, int c) {
#if __has_builtin(__builtin_amdgcn_sdot4)
  return __builtin_amdgcn_sdot4((int)a, (int)b, c, false);
#else
  int r = c;
#pragma unroll
  for (int i = 0; i < 4; i++) {
    int av = (int)(signed char)((a >> (8 * i)) & 255);
    int bv = (int)(signed char)((b >> (8 * i)) & 255);
    r += av * bv;
  }
  return r;
#endif
}

__device__ __forceinline__ float fsig(float x) {
  float e = __expf(-x);
  return __builtin_amdgcn_rcpf(1.0f + e);
}

// DPP quad_perm lane swaps (stay on VALU pipe, no LDS)
__device__ __forceinline__ int dpp_xor1(int x) {   // lanes q <-> q^1 : [1,0,3,2]
  return __builtin_amdgcn_update_dpp(0, x, 0xB1, 0xF, 0xF, true);
}
__device__ __forceinline__ int dpp_xor2(int x) {   // lanes q <-> q^2 : [2,3,0,1]
  return __builtin_amdgcn_update_dpp(0, x, 0x4E, 0xF, 0xF, true);
}
__device__ __forceinline__ float dpp_xor2_f(float x) {
  int r = __builtin_amdgcn_update_dpp(0, __float_as_int(x), 0x4E, 0xF, 0xF, true);
  return __int_as_float(r);
}

// ---------------- 1. FUSED front end: quant (blocks 0..511) + proj (512..1023) -------
// quant: Whh fp32 -> int8 rows with per-row scale (one wave per row).
// proj : pre[dir][t][unit][{i,f,g,o}] = bih+bhh + Wih @ embed[sent[t]].
// The two halves are independent (h-seed handled by k_lstm's s==0 scale trick),
// so fusing overlaps them and removes one launch/serialization gap.
__global__ __launch_bounds__(256) void k_front(const float* __restrict__ whh_f,
                                               const float* __restrict__ whh_b,
                                               uint32_t* __restrict__ q4,
                                               float* __restrict__ scales,
                                               const int* __restrict__ sentence,
                                               const float* __restrict__ embed,
                                               const float* __restrict__ Wih_f,
                                               const float* __restrict__ bih_f,
                                               const float* __restrict__ bhh_f,
                                               const float* __restrict__ Wih_b,
                                               const float* __restrict__ bih_b,
                                               const float* __restrict__ bhh_b,
                                               float* __restrict__ pre) {
  if (blockIdx.x < 512) {
    // ---------------- quant ----------------
    const int row  = (blockIdx.x * 256 + threadIdx.x) >> 6;  // 0..2047
    const int lane = threadIdx.x & 63;
    const int d = row >> 10, r = row & 1023;
    const float4 w = *(const float4*)((d ? whh_b : whh_f) + (long)r * HHD + lane * 4);
    float m = fmaxf(fmaxf(fabsf(w.x), fabsf(w.y)), fmaxf(fabsf(w.z), fabsf(w.w)));
#pragma unroll
    for (int off = 32; off; off >>= 1) m = fmaxf(m, __shfl_xor(m, off, 64));
    m = fmaxf(m, 1e-20f);
    const float inv = 127.f / m;
    int a = (int)rintf(w.x * inv), b = (int)rintf(w.y * inv);
    int c = (int)rintf(w.z * inv), e = (int)rintf(w.w * inv);
    q4[row * 64 + lane] = (uint32_t)(a & 255) | ((uint32_t)(b & 255) << 8) |
                          ((uint32_t)(c & 255) << 16) | ((uint32_t)(e & 255) << 24);
    if (lane == 0) scales[row] = m / 127.f;
    return;
  }
  // ---------------- proj ----------------
  const int bid2 = blockIdx.x - 512;      // 0..511
  const int dir  = bid2 >> 8;             // 0..1
  const int t0   = (bid2 & 255) * 8;
  const float* Wih = dir ? Wih_b : Wih_f;
  const float* bih = dir ? bih_b : bih_f;
  const float* bhh = dir ? bhh_b : bhh_f;

  __shared__ float xs[8][256];
  const int tid = threadIdx.x;
#pragma unroll
  for (int i = 0; i < 8; i++) {
    int s = sentence[t0 + i];
    xs[i][tid] = embed[(long)s * EMB + tid];
  }
  __syncthreads();

  const int r0 = tid * 4;
  float acc[4][8];
#pragma unroll
  for (int j = 0; j < 4; j++)
#pragma unroll
    for (int t = 0; t < 8; t++) acc[j][t] = 0.f;

  const float4* W4 = (const float4*)Wih;
  for (int kq = 0; kq < 64; kq++) {
    float4 w[4];
#pragma unroll
    for (int j = 0; j < 4; j++) w[j] = W4[(r0 + j) * 64 + kq];
#pragma unroll
    for (int t = 0; t < 8; t++) {
      float4 xv = ((const float4*)xs[t])[kq];
#pragma unroll
      for (int j = 0; j < 4; j++)
        acc[j][t] += w[j].x * xv.x + w[j].y * xv.y + w[j].z * xv.z + w[j].w * xv.w;
    }
  }
#pragma unroll
  for (int j = 0; j < 4; j++) {
    const int row = r0 + j;
    const int G  = row >> 8;             // 0:i 1:f 2:g 3:o (PyTorch order)
    const int uu = row & 255;            // unit
    float bsum = bih[row] + bhh[row];
#pragma unroll
    for (int t = 0; t < 8; t++)
      pre[(((long)(dir * SEQ + t0 + t)) * HHD + uu) * 4 + G] = acc[j][t] + bsum;
  }
}

// ---------------- 2. sequential LSTM: K-split quads + DPP reduction (R1, best) ------
// Lane L: q = L&3 (K-quarter), g = L>>2 (unit pair 2g,2g+1), p = q&1 (unit parity),
// half = q>>1 (0: gates i,f ; 1: gates g,o).  Slot j holds rows for lane q^j so a
// 2-level DPP quad butterfly lands each lane's own 2 gate sums in slot 0.
// h kept as int8 in LDS (|h|<1 -> fixed scale 1/127), double-buffered, 1 barrier/step.
__global__ __launch_bounds__(512, 2) void k_lstm(const uint32_t* __restrict__ q4,
                                                 const float* __restrict__ scales,
                                                 const float* __restrict__ pre,
                                                 const float* __restrict__ h0,
                                                 const float* __restrict__ c0,
                                                 float* __restrict__ hs) {
  const int dir  = blockIdx.x;
  const int L    = threadIdx.x;
  const int q    = L & 3;
  const int g    = L >> 2;       // 0..127
  const int p    = q & 1;
  const int half = q >> 1;
  const int u    = 2 * g + p;

  __shared__ __align__(16) uint8_t hbuf[2][256];

  const long base = (long)dir * GATES;

  uint4 wa[4][4], wb[4][4];
  const uint4* qq = (const uint4*)q4;
#pragma unroll
  for (int j = 0; j < 4; j++) {
    const int qj = q ^ j;
    const int rA = (2 * (qj >> 1)) * 256 + 2 * g + (qj & 1);
    const int rB = rA + 256;
#pragma unroll
    for (int k = 0; k < 4; k++) {
      wa[j][k] = qq[(base + rA) * 16 + 4 * q + k];   // own K-quarter q
      wb[j][k] = qq[(base + rB) * 16 + 4 * q + k];
    }
  }
  const int rown = (2 * half) * 256 + u;             // own A row (gate 2*half)
  const float sA = scales[base + rown];
  const float sB = scales[base + rown + 256];

  // seed h buffer 0 from h0 (scale 4/127: h0 ~ N(0,1), clamp at |4|)
  if (L < 256) {
    float v = h0[dir * HHD + L] * (127.f / 4.f);
    v = fminf(fmaxf(v, -127.f), 127.f);
    hbuf[0][L] = (uint8_t)(int)rintf(v);
  }
  float c_st = c0[dir * HHD + u];
  __syncthreads();

  const int t0 = dir ? (SEQ - 1) : 0;
  const long pstep = dir ? -(long)(HHD * 4) : (long)(HHD * 4);
  const long hstep = dir ? -(long)HHD : (long)HHD;
  const float* pp = pre + (long)dir * SEQ * (HHD * 4) + ((long)t0 * HHD + u) * 4 + 2 * half;
  float* hp       = hs  + (long)dir * SEQ * HHD + (long)t0 * HHD + u;
  const float gmul = half ? 2.f : 1.f;   // tanh(x) = 2*sig(2x)-1 trick, divergence-free
  const int write_h = ((L & 2) == 0);

  for (int s = 0; s < SEQ; s++) {
    const float2 pr = *(const float2*)pp;            // my 2 gate pre-activations

    const uint4* hq4 = (const uint4*)(hbuf[s & 1] + (q << 6));
    const uint4 h0v = hq4[0], h1v = hq4[1], h2v = hq4[2], h3v = hq4[3];

    int pa0 = 0, pa1 = 0, pa2 = 0, pa3 = 0;
    int pb0 = 0, pb1 = 0, pb2 = 0, pb3 = 0;
#pragma unroll
    for (int k = 0; k < 4; k++) {
      const uint4 hk = (k == 0) ? h0v : (k == 1) ? h1v : (k == 2) ? h2v : h3v;
      pa0 = sdot4(wa[0][k].x, hk.x, pa0); pa0 = sdot4(wa[0][k].y, hk.y, pa0);
      pa0 = sdot4(wa[0][k].z, hk.z, pa0); pa0 = sdot4(wa[0][k].w, hk.w, pa0);
      pa1 = sdot4(wa[1][k].x, hk.x, pa1); pa1 = sdot4(wa[1][k].y, hk.y, pa1);
      pa1 = sdot4(wa[1][k].z, hk.z, pa1); pa1 = sdot4(wa[1][k].w, hk.w, pa1);
      pa2 = sdot4(wa[2][k].x, hk.x, pa2); pa2 = sdot4(wa[2][k].y, hk.y, pa2);
      pa2 = sdot4(wa[2][k].z, hk.z, pa2); pa2 = sdot4(wa[2][k].w, hk.w, pa2);
      pa3 = sdot4(wa[3][k].x, hk.x, pa3); pa3 = sdot4(wa[3][k].y, hk.y, pa3);
      pa3 = sdot4(wa[3][k].z, hk.z, pa3); pa3 = sdot4(wa[3][k].w, hk.w, pa3);
      pb0 = sdot4(wb[0][k].x, hk.x, pb0); pb0 = sdot4(wb[0][k].y, hk.y, pb0);
      pb0 = sdot4(wb[0][k].z, hk.z, pb0); pb0 = sdot4(wb[0][k].w, hk.w, pb0);
      pb1 = sdot4(wb[1][k].x, hk.x, pb1); pb1 = sdot4(wb[1][k].y, hk.y, pb1);
      pb1 = sdot4(wb[1][k].z, hk.z, pb1); pb1 = sdot4(wb[1][k].w, hk.w, pb1);
      pb2 = sdot4(wb[2][k].x, hk.x, pb2); pb2 = sdot4(wb[2][k].y, hk.y, pb2);
      pb2 = sdot4(wb[2][k].z, hk.z, pb2); pb2 = sdot4(wb[2][k].w, hk.w, pb2);
      pb3 = sdot4(wb[3][k].x, hk.x, pb3); pb3 = sdot4(wb[3][k].y, hk.y, pb3);
      pb3 = sdot4(wb[3][k].z, hk.z, pb3); pb3 = sdot4(wb[3][k].w, hk.w, pb3);
    }
    // 2-level quad butterfly: slot0 of each lane ends with its own full row sums
    const int tA = pa0 + dpp_xor1(pa1);
    const int tA2 = pa2 + dpp_xor1(pa3);
    const int sumA = tA + dpp_xor2(tA2);
    const int tB = pb0 + dpp_xor1(pb1);
    const int tB2 = pb2 + dpp_xor1(pb3);
    const int sumB = tB + dpp_xor2(tB2);

    const float hsc = (s == 0) ? (4.f / 127.f) : (1.f / 127.f);
    const float gA = pr.x + sA * hsc * (float)sumA;  // i (even) | g (odd)
    const float gB = pr.y + sB * hsc * (float)sumB;  // f (even) | o (odd)

    // half0: v0=sig(gA)=i, v1=sig(gB)=f ; half1: v0=tanh(gA)=g, v1=sig(gB)=o
    const float v0 = fsig(gA * gmul) * gmul - (gmul - 1.f);
    const float v1 = fsig(gB);
    const float p0 = dpp_xor2_f(v0);                 // partner half's v0
    const float p1 = dpp_xor2_f(v1);
    const float iv = half ? p0 : v0;
    const float fv = half ? p1 : v1;
    const float gv = half ? v0 : p0;
    const float ov = half ? v1 : p1;

    c_st = fv * c_st + iv * gv;
    const float hv = ov * (2.f * fsig(2.f * c_st) - 1.f);

    if (write_h) {
      *hp = hv;
      hbuf[(s + 1) & 1][u] = (uint8_t)(int)rintf(hv * 127.f);  // |hv|<1
    }
    pp += pstep;
    hp += hstep;
    __syncthreads();
  }
}

// ---------------- 3. FUSED tail: feats for this chunk + CRF 12x12 fold ---------------
// Each of 16 blocks computes its own 128x12 feats (b_out + W_out.[hf;hb]) into LDS
// (and global feats for the gold-score kernel), then folds the 128 steps into a
// 12x12 log-semiring matrix -- k_feats dispatch eliminated.
__global__ __launch_bounds__(192) void k_tail(const float* __restrict__ hs,
                                              const float* __restrict__ W_out,
                                              const float* __restrict__ b_out,
                                              const float* __restrict__ trans,
                                              float* __restrict__ feats,
                                              float* __restrict__ Pc) {
  const int ch  = blockIdx.x;
  const int tid = threadIdx.x;

  __shared__ float Wl[12 * 520];
  __shared__ float fe[CLEN * NTAGS];
  for (int i = tid; i < 12 * 512; i += 192) Wl[(i / 512) * 520 + (i % 512)] = W_out[i];
  __syncthreads();

  // feats for timesteps [ch*128, ch*128+128): 1536 (t,n) pairs = 8 * 192
#pragma unroll
  for (int r = 0; r < 8; r++) {
    const int idx = r * 192 + tid;
    const int tl  = idx / 12, n = idx % 12;
    const int t   = ch * CLEN + tl;
    const float4* hf4 = (const float4*)(hs + (long)t * HHD);
    const float4* hb4 = (const float4*)(hs + (long)SEQ * HHD + (long)t * HHD);
    const float4* Wa  = (const float4*)&Wl[n * 520];
    const float4* Wb  = (const float4*)&Wl[n * 520 + 256];
    float acc = b_out[n];
#pragma unroll 8
    for (int j = 0; j < 64; j++) {
      float4 w = Wa[j], h = hf4[j];
      acc += w.x * h.x + w.y * h.y + w.z * h.z + w.w * h.w;
    }
#pragma unroll 8
    for (int j = 0; j < 64; j++) {
      float4 w = Wb[j], h = hb4[j];
      acc += w.x * h.x + w.y * h.y + w.z * h.z + w.w * h.w;
    }
    fe[tl * NTAGS + n] = acc;
    feats[t * NTAGS + n] = acc;        // still needed by gold score in k_crf_final
  }
  __syncthreads();

  // CRF fold (identical to previous k_crf_chunk, fe already resident)
  const int n   = tid & 15;
  const int p   = tid >> 4;                // 0..11
  const int nn  = (n < 12) ? n : 11;

  float trn[12];
#pragma unroll
  for (int j = 0; j < 12; j++) trn[j] = trans[nn * 12 + j];

  float Mv = trn[p] + fe[nn];              // A_{t0}[n,p]
  for (int t = 1; t < CLEN; t++) {
    float x[12], m = -1e30f;
#pragma unroll
    for (int j = 0; j < 12; j++) {
      x[j] = trn[j] + __shfl(Mv, (tid & 48) | j, 64);
      m = fmaxf(m, x[j]);
    }
    float ss = 0.f;
#pragma unroll
    for (int j = 0; j < 12; j++) ss += __expf(x[j] - m);
    Mv = fe[t * NTAGS + nn] + m + __logf(ss);
  }
  if (n < 12) Pc[ch * 144 + n * 12 + p] = Mv;
}

// ---------------- 4. combine chunk matrices + stop + gold score ----------------------
__global__ __launch_bounds__(128) void k_crf_final(const float* __restrict__ Pc,
                                                   const float* __restrict__ feats,
                                                   const int* __restrict__ tags,
                                                   const float* __restrict__ trans,
                                                   float* __restrict__ out) {
  __shared__ float Pl[CCH * 144];
  __shared__ float res[2];
  const int tid = threadIdx.x;
  for (int i = tid; i < CCH * 144; i += 128) Pl[i] = Pc[i];
  __syncthreads();

  if (tid < 64) {
    const int n  = tid;
    const int nn = (n < 12) ? n : 11;
    float fv = (n == START) ? 0.f : -10000.f;
    for (int c = 0; c < CCH; c++) {
      float x[12], m = -1e30f;
#pragma unroll
      for (int j = 0; j < 12; j++) {
        x[j] = Pl[c * 144 + nn * 12 + j] + __shfl(fv, j, 64);
        m = fmaxf(m, x[j]);
      }
      float ss = 0.f;
#pragma unroll
      for (int j = 0; j < 12; j++) ss += __expf(x[j] - m);
      fv = m + __logf(ss);
    }
    const float v = fv + trans[STOP * 12 + nn];
    float xs[12], m = -1e30f;
#pragma unroll
    for (int j = 0; j < 12; j++) {
      xs[j] = __shfl(v, j, 64);
      m = fmaxf(m, xs[j]);
    }
    float ss = 0.f;
#pragma unroll
    for (int j = 0; j < 12; j++) ss += __expf(xs[j] - m);
    if (tid == 0) res[0] = m + __logf(ss);
  } else {
    const int i = tid - 64;
    float gp = 0.f;
    for (int b = 0; b < 32; b++) {
      int t  = b * 64 + i;
      int tg = tags[t];
      int pv = (t == 0) ? START : tags[t - 1];
      gp += trans[tg * 12 + pv] + feats[t * NTAGS + tg];
    }
#pragma unroll
    for (int off = 32; off; off >>= 1) gp += __shfl_xor(gp, off, 64);
    if (i == 0) res[1] = gp + trans[STOP * 12 + tags[SEQ - 1]];
  }
  __syncthreads();
  if (tid == 0) out[0] = res[0] - res[1];
}

// -------------------------------------------------------------------------------------
extern "C" void kernel_launch(void* const* d_in, const int* in_sizes, int n_in,
                              void* d_out, int out_size, void* d_ws, size_t ws_size,
                              hipStream_t stream) {
  const int*   sentence = (const int*)  d_in[0];
  const int*   tags     = (const int*)  d_in[1];
  const float* embed    = (const float*)d_in[2];
  const float* Wih_f    = (const float*)d_in[3];
  const float* Whh_f    = (const float*)d_in[4];
  const float* bih_f    = (const float*)d_in[5];
  const float* bhh_f    = (const float*)d_in[6];
  const float* Wih_b    = (const float*)d_in[7];
  const float* Whh_b    = (const float*)d_in[8];
  const float* bih_b    = (const float*)d_in[9];
  const float* bhh_b    = (const float*)d_in[10];
  const float* W_out    = (const float*)d_in[11];
  const float* b_out    = (const float*)d_in[12];
  const float* h0       = (const float*)d_in[13];
  const float* c0       = (const float*)d_in[14];
  const float* trans    = (const float*)d_in[15];
  float* out = (float*)d_out;

  char* ws = (char*)d_ws;
  uint32_t* q4    = (uint32_t*)ws;                          // 512 KB
  float*    scales= (float*)(ws + (512l << 10));            // 8 KB
  float*    pre   = (float*)(ws + (1l  << 20));             // 16 MB : pre[2][2048][256][4]
  float*    hs    = (float*)(ws + (17l << 20));             // 4 MB  : hs[2][2048][256]
  float*    feats = (float*)(ws + (21l << 20));             // 96 KB : feats[2048][12]
  float*    Pc    = (float*)(ws + (21l << 20) + (128l<<10));// 9 KB  : Pc[16][12][12]

  k_front<<<1024, 256, 0, stream>>>(Whh_f, Whh_b, q4, scales,
                                    sentence, embed, Wih_f, bih_f, bhh_f,
                                    Wih_b, bih_b, bhh_b, pre);
  k_lstm<<<2, 512, 0, stream>>>(q4, scales, pre, h0, c0, hs);
  k_tail<<<CCH, 192, 0, stream>>>(hs, W_out, b_out, trans, feats, Pc);
  k_crf_final<<<1, 128, 0, stream>>>(Pc, feats, tags, trans, out);
}

// Round 9
// 1821.287 us; speedup vs baseline: 2.2847x; 1.0381x over previous
//
#include <hip/hip_runtime.h>
#include <hip/hip_bf16.h>
#include <stdint.h>

#define SEQ   2048
#define EMB   256
#define HHD   256      // per-direction hidden
#define GATES 1024     // 4*HHD
#define NTAGS 12
#define START 10
#define STOP  11
#define CCH   16       // CRF chunks
#define CLEN  128      // steps per chunk

__device__ __forceinline__ int sdot4(uint32_t a, uint32_t b, int c) {
#if __has_builtin(__builtin_amdgcn_sdot4)
  return __builtin_amdgcn_sdot4((int)a, (int)b, c, false);
#else
  int r = c;
#pragma unroll
  for (int i = 0; i < 4; i++) {
    int av = (int)(signed char)((a >> (8 * i)) & 255);
    int bv = (int)(signed char)((b >> (8 * i)) & 255);
    r += av * bv;
  }
  return r;
#endif
}

__device__ __forceinline__ float fsig(float x) {
  float e = __expf(-x);
  return __builtin_amdgcn_rcpf(1.0f + e);
}

// DPP quad_perm lane swaps (stay on VALU pipe, no LDS)
__device__ __forceinline__ int dpp_xor1(int x) {   // lanes q <-> q^1 : [1,0,3,2]
  return __builtin_amdgcn_update_dpp(0, x, 0xB1, 0xF, 0xF, true);
}
__device__ __forceinline__ int dpp_xor2(int x) {   // lanes q <-> q^2 : [2,3,0,1]
  return __builtin_amdgcn_update_dpp(0, x, 0x4E, 0xF, 0xF, true);
}
__device__ __forceinline__ float dpp_xor2_f(float x) {
  int r = __builtin_amdgcn_update_dpp(0, __float_as_int(x), 0x4E, 0xF, 0xF, true);
  return __int_as_float(r);
}

// ---------------- 1. FUSED front end: quant (blocks 0..511) + proj (512..1023) -------
// quant: Whh fp32 -> int8 rows with per-row scale (one wave per row).
// proj : pre[dir][t][unit][{i,f,g,o}] = bih+bhh + Wih @ embed[sent[t]].
// proj uses THREAD-PER-UNIT mapping: each thread computes all 4 gate rows of one
// unit -> the pre store is one coalesced float4 per (t,unit) (vs 4 scattered
// scalars).  The two halves are independent (h-seed handled by k_lstm's s==0
// scale trick); fusing overlaps them and removes one launch gap.
__global__ __launch_bounds__(256) void k_front(const float* __restrict__ whh_f,
                                               const float* __restrict__ whh_b,
                                               uint32_t* __restrict__ q4,
                                               float* __restrict__ scales,
                                               const int* __restrict__ sentence,
                                               const float* __restrict__ embed,
                                               const float* __restrict__ Wih_f,
                                               const float* __restrict__ bih_f,
                                               const float* __restrict__ bhh_f,
                                               const float* __restrict__ Wih_b,
                                               const float* __restrict__ bih_b,
                                               const float* __restrict__ bhh_b,
                                               float* __restrict__ pre) {
  if (blockIdx.x < 512) {
    // ---------------- quant ----------------
    const int row  = (blockIdx.x * 256 + threadIdx.x) >> 6;  // 0..2047
    const int lane = threadIdx.x & 63;
    const int d = row >> 10, r = row & 1023;
    const float4 w = *(const float4*)((d ? whh_b : whh_f) + (long)r * HHD + lane * 4);
    float m = fmaxf(fmaxf(fabsf(w.x), fabsf(w.y)), fmaxf(fabsf(w.z), fabsf(w.w)));
#pragma unroll
    for (int off = 32; off; off >>= 1) m = fmaxf(m, __shfl_xor(m, off, 64));
    m = fmaxf(m, 1e-20f);
    const float inv = 127.f / m;
    int a = (int)rintf(w.x * inv), b = (int)rintf(w.y * inv);
    int c = (int)rintf(w.z * inv), e = (int)rintf(w.w * inv);
    q4[row * 64 + lane] = (uint32_t)(a & 255) | ((uint32_t)(b & 255) << 8) |
                          ((uint32_t)(c & 255) << 16) | ((uint32_t)(e & 255) << 24);
    if (lane == 0) scales[row] = m / 127.f;
    return;
  }
  // ---------------- proj (thread-per-unit) ----------------
  const int bid2 = blockIdx.x - 512;      // 0..511
  const int dir  = bid2 >> 8;             // 0..1
  const int t0   = (bid2 & 255) * 8;
  const float* Wih = dir ? Wih_b : Wih_f;
  const float* bih = dir ? bih_b : bih_f;
  const float* bhh = dir ? bhh_b : bhh_f;

  __shared__ float xs[8][256];
  const int uu = threadIdx.x;             // unit 0..255
#pragma unroll
  for (int i = 0; i < 8; i++) {
    int s = sentence[t0 + i];
    xs[i][uu] = embed[(long)s * EMB + uu];
  }
  __syncthreads();

  float acc[4][8];                        // [gate][t]
#pragma unroll
  for (int j = 0; j < 4; j++)
#pragma unroll
    for (int t = 0; t < 8; t++) acc[j][t] = 0.f;

  const float4* W4 = (const float4*)Wih;
  for (int kq = 0; kq < 64; kq++) {
    float4 w[4];
#pragma unroll
    for (int j = 0; j < 4; j++) w[j] = W4[(j * 256 + uu) * 64 + kq];  // row j*256+uu
#pragma unroll
    for (int t = 0; t < 8; t++) {
      float4 xv = ((const float4*)xs[t])[kq];
#pragma unroll
      for (int j = 0; j < 4; j++)
        acc[j][t] += w[j].x * xv.x + w[j].y * xv.y + w[j].z * xv.z + w[j].w * xv.w;
    }
  }
  float bs[4];
#pragma unroll
  for (int j = 0; j < 4; j++) bs[j] = bih[j * 256 + uu] + bhh[j * 256 + uu];
#pragma unroll
  for (int t = 0; t < 8; t++) {
    float4 o = {acc[0][t] + bs[0], acc[1][t] + bs[1],
                acc[2][t] + bs[2], acc[3][t] + bs[3]};
    *(float4*)&pre[(((long)(dir * SEQ + t0 + t)) * HHD + uu) * 4] = o;  // coalesced
  }
}

// ---------------- 2. sequential LSTM: K-split quads + DPP reduction (R1, best) ------
// Lane L: q = L&3 (K-quarter), g = L>>2 (unit pair 2g,2g+1), p = q&1 (unit parity),
// half = q>>1 (0: gates i,f ; 1: gates g,o).  Slot j holds rows for lane q^j so a
// 2-level DPP quad butterfly lands each lane's own 2 gate sums in slot 0.
// h kept as int8 in LDS (|h|<1 -> fixed scale 1/127), double-buffered, 1 barrier/step.
__global__ __launch_bounds__(512, 2) void k_lstm(const uint32_t* __restrict__ q4,
                                                 const float* __restrict__ scales,
                                                 const float* __restrict__ pre,
                                                 const float* __restrict__ h0,
                                                 const float* __restrict__ c0,
                                                 float* __restrict__ hs) {
  const int dir  = blockIdx.x;
  const int L    = threadIdx.x;
  const int q    = L & 3;
  const int g    = L >> 2;       // 0..127
  const int p    = q & 1;
  const int half = q >> 1;
  const int u    = 2 * g + p;

  __shared__ __align__(16) uint8_t hbuf[2][256];

  const long base = (long)dir * GATES;

  uint4 wa[4][4], wb[4][4];
  const uint4* qq = (const uint4*)q4;
#pragma unroll
  for (int j = 0; j < 4; j++) {
    const int qj = q ^ j;
    const int rA = (2 * (qj >> 1)) * 256 + 2 * g + (qj & 1);
    const int rB = rA + 256;
#pragma unroll
    for (int k = 0; k < 4; k++) {
      wa[j][k] = qq[(base + rA) * 16 + 4 * q + k];   // own K-quarter q
      wb[j][k] = qq[(base + rB) * 16 + 4 * q + k];
    }
  }
  const int rown = (2 * half) * 256 + u;             // own A row (gate 2*half)
  const float sA = scales[base + rown];
  const float sB = scales[base + rown + 256];

  // seed h buffer 0 from h0 (scale 4/127: h0 ~ N(0,1), clamp at |4|)
  if (L < 256) {
    float v = h0[dir * HHD + L] * (127.f / 4.f);
    v = fminf(fmaxf(v, -127.f), 127.f);
    hbuf[0][L] = (uint8_t)(int)rintf(v);
  }
  float c_st = c0[dir * HHD + u];
  __syncthreads();

  const int t0 = dir ? (SEQ - 1) : 0;
  const long pstep = dir ? -(long)(HHD * 4) : (long)(HHD * 4);
  const long hstep = dir ? -(long)HHD : (long)HHD;
  const float* pp = pre + (long)dir * SEQ * (HHD * 4) + ((long)t0 * HHD + u) * 4 + 2 * half;
  float* hp       = hs  + (long)dir * SEQ * HHD + (long)t0 * HHD + u;
  const float gmul = half ? 2.f : 1.f;   // tanh(x) = 2*sig(2x)-1 trick, divergence-free
  const int write_h = ((L & 2) == 0);

  for (int s = 0; s < SEQ; s++) {
    const float2 pr = *(const float2*)pp;            // my 2 gate pre-activations

    const uint4* hq4 = (const uint4*)(hbuf[s & 1] + (q << 6));
    const uint4 h0v = hq4[0], h1v = hq4[1], h2v = hq4[2], h3v = hq4[3];

    int pa0 = 0, pa1 = 0, pa2 = 0, pa3 = 0;
    int pb0 = 0, pb1 = 0, pb2 = 0, pb3 = 0;
#pragma unroll
    for (int k = 0; k < 4; k++) {
      const uint4 hk = (k == 0) ? h0v : (k == 1) ? h1v : (k == 2) ? h2v : h3v;
      pa0 = sdot4(wa[0][k].x, hk.x, pa0); pa0 = sdot4(wa[0][k].y, hk.y, pa0);
      pa0 = sdot4(wa[0][k].z, hk.z, pa0); pa0 = sdot4(wa[0][k].w, hk.w, pa0);
      pa1 = sdot4(wa[1][k].x, hk.x, pa1); pa1 = sdot4(wa[1][k].y, hk.y, pa1);
      pa1 = sdot4(wa[1][k].z, hk.z, pa1); pa1 = sdot4(wa[1][k].w, hk.w, pa1);
      pa2 = sdot4(wa[2][k].x, hk.x, pa2); pa2 = sdot4(wa[2][k].y, hk.y, pa2);
      pa2 = sdot4(wa[2][k].z, hk.z, pa2); pa2 = sdot4(wa[2][k].w, hk.w, pa2);
      pa3 = sdot4(wa[3][k].x, hk.x, pa3); pa3 = sdot4(wa[3][k].y, hk.y, pa3);
      pa3 = sdot4(wa[3][k].z, hk.z, pa3); pa3 = sdot4(wa[3][k].w, hk.w, pa3);
      pb0 = sdot4(wb[0][k].x, hk.x, pb0); pb0 = sdot4(wb[0][k].y, hk.y, pb0);
      pb0 = sdot4(wb[0][k].z, hk.z, pb0); pb0 = sdot4(wb[0][k].w, hk.w, pb0);
      pb1 = sdot4(wb[1][k].x, hk.x, pb1); pb1 = sdot4(wb[1][k].y, hk.y, pb1);
      pb1 = sdot4(wb[1][k].z, hk.z, pb1); pb1 = sdot4(wb[1][k].w, hk.w, pb1);
      pb2 = sdot4(wb[2][k].x, hk.x, pb2); pb2 = sdot4(wb[2][k].y, hk.y, pb2);
      pb2 = sdot4(wb[2][k].z, hk.z, pb2); pb2 = sdot4(wb[2][k].w, hk.w, pb2);
      pb3 = sdot4(wb[3][k].x, hk.x, pb3); pb3 = sdot4(wb[3][k].y, hk.y, pb3);
      pb3 = sdot4(wb[3][k].z, hk.z, pb3); pb3 = sdot4(wb[3][k].w, hk.w, pb3);
    }
    // 2-level quad butterfly: slot0 of each lane ends with its own full row sums
    const int tA = pa0 + dpp_xor1(pa1);
    const int tA2 = pa2 + dpp_xor1(pa3);
    const int sumA = tA + dpp_xor2(tA2);
    const int tB = pb0 + dpp_xor1(pb1);
    const int tB2 = pb2 + dpp_xor1(pb3);
    const int sumB = tB + dpp_xor2(tB2);

    const float hsc = (s == 0) ? (4.f / 127.f) : (1.f / 127.f);
    const float gA = pr.x + sA * hsc * (float)sumA;  // i (even) | g (odd)
    const float gB = pr.y + sB * hsc * (float)sumB;  // f (even) | o (odd)

    // half0: v0=sig(gA)=i, v1=sig(gB)=f ; half1: v0=tanh(gA)=g, v1=sig(gB)=o
    const float v0 = fsig(gA * gmul) * gmul - (gmul - 1.f);
    const float v1 = fsig(gB);
    const float p0 = dpp_xor2_f(v0);                 // partner half's v0
    const float p1 = dpp_xor2_f(v1);
    const float iv = half ? p0 : v0;
    const float fv = half ? p1 : v1;
    const float gv = half ? v0 : p0;
    const float ov = half ? v1 : p1;

    c_st = fv * c_st + iv * gv;
    const float hv = ov * (2.f * fsig(2.f * c_st) - 1.f);

    if (write_h) {
      *hp = hv;
      hbuf[(s + 1) & 1][u] = (uint8_t)(int)rintf(hv * 127.f);  // |hv|<1
    }
    pp += pstep;
    hp += hstep;
    __syncthreads();
  }
}

// ---------------- 3. feats[t][n] = b_out[n] + W_out[n] . [hf[t]; hb[t]] --------------
__global__ __launch_bounds__(192) void k_feats(const float* __restrict__ hs,
                                               const float* __restrict__ W_out,
                                               const float* __restrict__ b_out,
                                               float* __restrict__ feats) {
  __shared__ float Wl[12 * 520];
  const int tid = threadIdx.x;
  for (int i = tid; i < 12 * 512; i += 192) Wl[(i / 512) * 520 + (i % 512)] = W_out[i];
  __syncthreads();

  const int tl = tid / 12, n = tid % 12;
  const int t = blockIdx.x * 16 + tl;
  const float4* hf4 = (const float4*)(hs + (long)t * HHD);
  const float4* hb4 = (const float4*)(hs + (long)SEQ * HHD + (long)t * HHD);
  const float4* Wa  = (const float4*)&Wl[n * 520];
  const float4* Wb  = (const float4*)&Wl[n * 520 + 256];

  float acc = b_out[n];
#pragma unroll 8
  for (int j = 0; j < 64; j++) {
    float4 w = Wa[j], h = hf4[j];
    acc += w.x * h.x + w.y * h.y + w.z * h.z + w.w * h.w;
  }
#pragma unroll 8
  for (int j = 0; j < 64; j++) {
    float4 w = Wb[j], h = hb4[j];
    acc += w.x * h.x + w.y * h.y + w.z * h.z + w.w * h.w;
  }
  feats[t * NTAGS + n] = acc;
}

// ---------------- 4. CRF chunk: fold 128 steps into a 12x12 log-semiring matrix ------
__global__ __launch_bounds__(192) void k_crf_chunk(const float* __restrict__ feats,
                                                   const float* __restrict__ trans,
                                                   float* __restrict__ Pc) {
  const int ch  = blockIdx.x;
  const int tid = threadIdx.x;
  const int n   = tid & 15;
  const int p   = tid >> 4;                // 0..11
  const int nn  = (n < 12) ? n : 11;

  __shared__ float fe[CLEN * NTAGS];
  for (int i = tid; i < CLEN * NTAGS; i += 192) fe[i] = feats[ch * CLEN * NTAGS + i];
  __syncthreads();

  float trn[12];
#pragma unroll
  for (int j = 0; j < 12; j++) trn[j] = trans[nn * 12 + j];

  float Mv = trans[nn * 12 + p] + fe[nn];  // A_{t0}[n,p]
  for (int t = 1; t < CLEN; t++) {
    float x[12], m = -1e30f;
#pragma unroll
    for (int j = 0; j < 12; j++) {
      x[j] = trn[j] + __shfl(Mv, (tid & 48) | j, 64);
      m = fmaxf(m, x[j]);
    }
    float ss = 0.f;
#pragma unroll
    for (int j = 0; j < 12; j++) ss += __expf(x[j] - m);
    Mv = fe[t * NTAGS + nn] + m + __logf(ss);
  }
  if (n < 12) Pc[ch * 144 + n * 12 + p] = Mv;
}

// ---------------- 5. combine chunk matrices + stop + gold score ----------------------
__global__ __launch_bounds__(128) void k_crf_final(const float* __restrict__ Pc,
                                                   const float* __restrict__ feats,
                                                   const int* __restrict__ tags,
                                                   const float* __restrict__ trans,
                                                   float* __restrict__ out) {
  __shared__ float Pl[CCH * 144];
  __shared__ float res[2];
  const int tid = threadIdx.x;
  for (int i = tid; i < CCH * 144; i += 128) Pl[i] = Pc[i];
  __syncthreads();

  if (tid < 64) {
    const int n  = tid;
    const int nn = (n < 12) ? n : 11;
    float fv = (n == START) ? 0.f : -10000.f;
    for (int c = 0; c < CCH; c++) {
      float x[12], m = -1e30f;
#pragma unroll
      for (int j = 0; j < 12; j++) {
        x[j] = Pl[c * 144 + nn * 12 + j] + __shfl(fv, j, 64);
        m = fmaxf(m, x[j]);
      }
      float ss = 0.f;
#pragma unroll
      for (int j = 0; j < 12; j++) ss += __expf(x[j] - m);
      fv = m + __logf(ss);
    }
    const float v = fv + trans[STOP * 12 + nn];
    float xs[12], m = -1e30f;
#pragma unroll
    for (int j = 0; j < 12; j++) {
      xs[j] = __shfl(v, j, 64);
      m = fmaxf(m, xs[j]);
    }
    float ss = 0.f;
#pragma unroll
    for (int j = 0; j < 12; j++) ss += __expf(xs[j] - m);
    if (tid == 0) res[0] = m + __logf(ss);
  } else {
    const int i = tid - 64;
    float gp = 0.f;
    for (int b = 0; b < 32; b++) {
      int t  = b * 64 + i;
      int tg = tags[t];
      int pv = (t == 0) ? START : tags[t - 1];
      gp += trans[tg * 12 + pv] + feats[t * NTAGS + tg];
    }
#pragma unroll
    for (int off = 32; off; off >>= 1) gp += __shfl_xor(gp, off, 64);
    if (i == 0) res[1] = gp + trans[STOP * 12 + tags[SEQ - 1]];
  }
  __syncthreads();
  if (tid == 0) out[0] = res[0] - res[1];
}

// -------------------------------------------------------------------------------------
extern "C" void kernel_launch(void* const* d_in, const int* in_sizes, int n_in,
                              void* d_out, int out_size, void* d_ws, size_t ws_size,
                              hipStream_t stream) {
  const int*   sentence = (const int*)  d_in[0];
  const int*   tags     = (const int*)  d_in[1];
  const float* embed    = (const float*)d_in[2];
  const float* Wih_f    = (const float*)d_in[3];
  const float* Whh_f    = (const float*)d_in[4];
  const float* bih_f    = (const float*)d_in[5];
  const float* bhh_f    = (const float*)d_in[6];
  const float* Wih_b    = (const float*)d_in[7];
  const float* Whh_b    = (const float*)d_in[8];
  const float* bih_b    = (const float*)d_in[9];
  const float* bhh_b    = (const float*)d_in[10];
  const float* W_out    = (const float*)d_in[11];
  const float* b_out    = (const float*)d_in[12];
  const float* h0       = (const float*)d_in[13];
  const float* c0       = (const float*)d_in[14];
  const float* trans    = (const float*)d_in[15];
  float* out = (float*)d_out;

  char* ws = (char*)d_ws;
  uint32_t* q4    = (uint32_t*)ws;                          // 512 KB
  float*    scales= (float*)(ws + (512l << 10));            // 8 KB
  float*    pre   = (float*)(ws + (1l  << 20));             // 16 MB : pre[2][2048][256][4]
  float*    hs    = (float*)(ws + (17l << 20));             // 4 MB  : hs[2][2048][256]
  float*    feats = (float*)(ws + (21l << 20));             // 96 KB : feats[2048][12]
  float*    Pc    = (float*)(ws + (21l << 20) + (128l<<10));// 9 KB  : Pc[16][12][12]

  k_front<<<1024, 256, 0, stream>>>(Whh_f, Whh_b, q4, scales,
                                    sentence, embed, Wih_f, bih_f, bhh_f,
                                    Wih_b, bih_b, bhh_b, pre);
  k_lstm<<<2, 512, 0, stream>>>(q4, scales, pre, h0, c0, hs);
  k_feats<<<128, 192, 0, stream>>>(hs, W_out, b_out, feats);
  k_crf_chunk<<<CCH, 192, 0, stream>>>(feats, trans, Pc);
  k_crf_final<<<1, 128, 0, stream>>>(Pc, feats, tags, trans, out);
}

// Round 10
// 1798.409 us; speedup vs baseline: 2.3138x; 1.0127x over previous
//
#include <hip/hip_runtime.h>
#include <hip/hip_bf16.h>
#include <stdint.h>

#define SEQ   2048
#define EMB   256
#define HHD   256      // per-direction hidden
#define GATES 1024     // 4*HHD
#define NTAGS 12
#define START 10
#define STOP  11
#define CCH   16       // CRF chunks
#define CLEN  128      // steps per chunk

__device__ __forceinline__ int sdot4(uint32_t a, uint32_t b, int c) {
#if __has_builtin(__builtin_amdgcn_sdot4)
  return __builtin_amdgcn_sdot4((int)a, (int)b, c, false);
#else
  int r = c;
#pragma unroll
  for (int i = 0; i < 4; i++) {
    int av = (int)(signed char)((a >> (8 * i)) & 255);
    int bv = (int)(signed char)((b >> (8 * i)) & 255);
    r += av * bv;
  }
  return r;
#endif
}

__device__ __forceinline__ float fsig(float x) {
  float e = __expf(-x);
  return __builtin_amdgcn_rcpf(1.0f + e);
}

// DPP quad_perm lane swaps (stay on VALU pipe, no LDS)
__device__ __forceinline__ int dpp_xor1(int x) {   // lanes q <-> q^1 : [1,0,3,2]
  return __builtin_amdgcn_update_dpp(0, x, 0xB1, 0xF, 0xF, true);
}
__device__ __forceinline__ int dpp_xor2(int x) {   // lanes q <-> q^2 : [2,3,0,1]
  return __builtin_amdgcn_update_dpp(0, x, 0x4E, 0xF, 0xF, true);
}
__device__ __forceinline__ float dpp_xor2_f(float x) {
  int r = __builtin_amdgcn_update_dpp(0, __float_as_int(x), 0x4E, 0xF, 0xF, true);
  return __int_as_float(r);
}

// ---------------- 1. FUSED front end: quant (blocks 0..511) + proj (512..1023) -------
// quant: Whh fp32 -> int8 rows with per-row scale (one wave per row).
// proj : pre[dir][t][unit][{i,f,g,o}] = bih+bhh + Wih @ embed[sent[t]].
// proj is thread-per-unit with J-OUTER / KQ-INNER loop order: each thread streams
// ONE W-row to completion (per-wave active set = 64 rows x 128B = 8KB, L1-resident)
// instead of keeping all 1024 rows of the block hot (128KB >> 32KB L1 -> ~8x L2
// overfetch).  Per-accumulator kq order unchanged -> bit-identical pre.
__global__ __launch_bounds__(256) void k_front(const float* __restrict__ whh_f,
                                               const float* __restrict__ whh_b,
                                               uint32_t* __restrict__ q4,
                                               float* __restrict__ scales,
                                               const int* __restrict__ sentence,
                                               const float* __restrict__ embed,
                                               const float* __restrict__ Wih_f,
                                               const float* __restrict__ bih_f,
                                               const float* __restrict__ bhh_f,
                                               const float* __restrict__ Wih_b,
                                               const float* __restrict__ bih_b,
                                               const float* __restrict__ bhh_b,
                                               float* __restrict__ pre) {
  if (blockIdx.x < 512) {
    // ---------------- quant ----------------
    const int row  = (blockIdx.x * 256 + threadIdx.x) >> 6;  // 0..2047
    const int lane = threadIdx.x & 63;
    const int d = row >> 10, r = row & 1023;
    const float4 w = *(const float4*)((d ? whh_b : whh_f) + (long)r * HHD + lane * 4);
    float m = fmaxf(fmaxf(fabsf(w.x), fabsf(w.y)), fmaxf(fabsf(w.z), fabsf(w.w)));
#pragma unroll
    for (int off = 32; off; off >>= 1) m = fmaxf(m, __shfl_xor(m, off, 64));
    m = fmaxf(m, 1e-20f);
    const float inv = 127.f / m;
    int a = (int)rintf(w.x * inv), b = (int)rintf(w.y * inv);
    int c = (int)rintf(w.z * inv), e = (int)rintf(w.w * inv);
    q4[row * 64 + lane] = (uint32_t)(a & 255) | ((uint32_t)(b & 255) << 8) |
                          ((uint32_t)(c & 255) << 16) | ((uint32_t)(e & 255) << 24);
    if (lane == 0) scales[row] = m / 127.f;
    return;
  }
  // ---------------- proj (thread-per-unit, j-outer) ----------------
  const int bid2 = blockIdx.x - 512;      // 0..511
  const int dir  = bid2 >> 8;             // 0..1
  const int t0   = (bid2 & 255) * 8;
  const float* Wih = dir ? Wih_b : Wih_f;
  const float* bih = dir ? bih_b : bih_f;
  const float* bhh = dir ? bhh_b : bhh_f;

  __shared__ float xs[8][256];
  const int uu = threadIdx.x;             // unit 0..255
#pragma unroll
  for (int i = 0; i < 8; i++) {
    int s = sentence[t0 + i];
    xs[i][uu] = embed[(long)s * EMB + uu];
  }
  __syncthreads();

  float acc[4][8];                        // [gate][t]
#pragma unroll
  for (int j = 0; j < 4; j++)
#pragma unroll
    for (int t = 0; t < 8; t++) acc[j][t] = 0.f;

  const float4* W4 = (const float4*)Wih;
#pragma unroll
  for (int j = 0; j < 4; j++) {
    const float4* Wrow = W4 + (long)(j * 256 + uu) * 64;   // this thread's row j
    for (int kq = 0; kq < 64; kq++) {
      const float4 w = Wrow[kq];                           // streamed, L1-resident
#pragma unroll
      for (int t = 0; t < 8; t++) {
        const float4 xv = ((const float4*)xs[t])[kq];
        acc[j][t] += w.x * xv.x + w.y * xv.y + w.z * xv.z + w.w * xv.w;
      }
    }
  }
  float bs[4];
#pragma unroll
  for (int j = 0; j < 4; j++) bs[j] = bih[j * 256 + uu] + bhh[j * 256 + uu];
#pragma unroll
  for (int t = 0; t < 8; t++) {
    float4 o = {acc[0][t] + bs[0], acc[1][t] + bs[1],
                acc[2][t] + bs[2], acc[3][t] + bs[3]};
    *(float4*)&pre[(((long)(dir * SEQ + t0 + t)) * HHD + uu) * 4] = o;  // coalesced
  }
}

// ---------------- 2. sequential LSTM: K-split quads + DPP reduction (R1, best) ------
// Lane L: q = L&3 (K-quarter), g = L>>2 (unit pair 2g,2g+1), p = q&1 (unit parity),
// half = q>>1 (0: gates i,f ; 1: gates g,o).  Slot j holds rows for lane q^j so a
// 2-level DPP quad butterfly lands each lane's own 2 gate sums in slot 0.
// h kept as int8 in LDS (|h|<1 -> fixed scale 1/127), double-buffered, 1 barrier/step.
__global__ __launch_bounds__(512, 2) void k_lstm(const uint32_t* __restrict__ q4,
                                                 const float* __restrict__ scales,
                                                 const float* __restrict__ pre,
                                                 const float* __restrict__ h0,
                                                 const float* __restrict__ c0,
                                                 float* __restrict__ hs) {
  const int dir  = blockIdx.x;
  const int L    = threadIdx.x;
  const int q    = L & 3;
  const int g    = L >> 2;       // 0..127
  const int p    = q & 1;
  const int half = q >> 1;
  const int u    = 2 * g + p;

  __shared__ __align__(16) uint8_t hbuf[2][256];

  const long base = (long)dir * GATES;

  uint4 wa[4][4], wb[4][4];
  const uint4* qq = (const uint4*)q4;
#pragma unroll
  for (int j = 0; j < 4; j++) {
    const int qj = q ^ j;
    const int rA = (2 * (qj >> 1)) * 256 + 2 * g + (qj & 1);
    const int rB = rA + 256;
#pragma unroll
    for (int k = 0; k < 4; k++) {
      wa[j][k] = qq[(base + rA) * 16 + 4 * q + k];   // own K-quarter q
      wb[j][k] = qq[(base + rB) * 16 + 4 * q + k];
    }
  }
  const int rown = (2 * half) * 256 + u;             // own A row (gate 2*half)
  const float sA = scales[base + rown];
  const float sB = scales[base + rown + 256];

  // seed h buffer 0 from h0 (scale 4/127: h0 ~ N(0,1), clamp at |4|)
  if (L < 256) {
    float v = h0[dir * HHD + L] * (127.f / 4.f);
    v = fminf(fmaxf(v, -127.f), 127.f);
    hbuf[0][L] = (uint8_t)(int)rintf(v);
  }
  float c_st = c0[dir * HHD + u];
  __syncthreads();

  const int t0 = dir ? (SEQ - 1) : 0;
  const long pstep = dir ? -(long)(HHD * 4) : (long)(HHD * 4);
  const long hstep = dir ? -(long)HHD : (long)HHD;
  const float* pp = pre + (long)dir * SEQ * (HHD * 4) + ((long)t0 * HHD + u) * 4 + 2 * half;
  float* hp       = hs  + (long)dir * SEQ * HHD + (long)t0 * HHD + u;
  const float gmul = half ? 2.f : 1.f;   // tanh(x) = 2*sig(2x)-1 trick, divergence-free
  const int write_h = ((L & 2) == 0);

  for (int s = 0; s < SEQ; s++) {
    const float2 pr = *(const float2*)pp;            // my 2 gate pre-activations

    const uint4* hq4 = (const uint4*)(hbuf[s & 1] + (q << 6));
    const uint4 h0v = hq4[0], h1v = hq4[1], h2v = hq4[2], h3v = hq4[3];

    int pa0 = 0, pa1 = 0, pa2 = 0, pa3 = 0;
    int pb0 = 0, pb1 = 0, pb2 = 0, pb3 = 0;
#pragma unroll
    for (int k = 0; k < 4; k++) {
      const uint4 hk = (k == 0) ? h0v : (k == 1) ? h1v : (k == 2) ? h2v : h3v;
      pa0 = sdot4(wa[0][k].x, hk.x, pa0); pa0 = sdot4(wa[0][k].y, hk.y, pa0);
      pa0 = sdot4(wa[0][k].z, hk.z, pa0); pa0 = sdot4(wa[0][k].w, hk.w, pa0);
      pa1 = sdot4(wa[1][k].x, hk.x, pa1); pa1 = sdot4(wa[1][k].y, hk.y, pa1);
      pa1 = sdot4(wa[1][k].z, hk.z, pa1); pa1 = sdot4(wa[1][k].w, hk.w, pa1);
      pa2 = sdot4(wa[2][k].x, hk.x, pa2); pa2 = sdot4(wa[2][k].y, hk.y, pa2);
      pa2 = sdot4(wa[2][k].z, hk.z, pa2); pa2 = sdot4(wa[2][k].w, hk.w, pa2);
      pa3 = sdot4(wa[3][k].x, hk.x, pa3); pa3 = sdot4(wa[3][k].y, hk.y, pa3);
      pa3 = sdot4(wa[3][k].z, hk.z, pa3); pa3 = sdot4(wa[3][k].w, hk.w, pa3);
      pb0 = sdot4(wb[0][k].x, hk.x, pb0); pb0 = sdot4(wb[0][k].y, hk.y, pb0);
      pb0 = sdot4(wb[0][k].z, hk.z, pb0); pb0 = sdot4(wb[0][k].w, hk.w, pb0);
      pb1 = sdot4(wb[1][k].x, hk.x, pb1); pb1 = sdot4(wb[1][k].y, hk.y, pb1);
      pb1 = sdot4(wb[1][k].z, hk.z, pb1); pb1 = sdot4(wb[1][k].w, hk.w, pb1);
      pb2 = sdot4(wb[2][k].x, hk.x, pb2); pb2 = sdot4(wb[2][k].y, hk.y, pb2);
      pb2 = sdot4(wb[2][k].z, hk.z, pb2); pb2 = sdot4(wb[2][k].w, hk.w, pb2);
      pb3 = sdot4(wb[3][k].x, hk.x, pb3); pb3 = sdot4(wb[3][k].y, hk.y, pb3);
      pb3 = sdot4(wb[3][k].z, hk.z, pb3); pb3 = sdot4(wb[3][k].w, hk.w, pb3);
    }
    // 2-level quad butterfly: slot0 of each lane ends with its own full row sums
    const int tA = pa0 + dpp_xor1(pa1);
    const int tA2 = pa2 + dpp_xor1(pa3);
    const int sumA = tA + dpp_xor2(tA2);
    const int tB = pb0 + dpp_xor1(pb1);
    const int tB2 = pb2 + dpp_xor1(pb3);
    const int sumB = tB + dpp_xor2(tB2);

    const float hsc = (s == 0) ? (4.f / 127.f) : (1.f / 127.f);
    const float gA = pr.x + sA * hsc * (float)sumA;  // i (even) | g (odd)
    const float gB = pr.y + sB * hsc * (float)sumB;  // f (even) | o (odd)

    // half0: v0=sig(gA)=i, v1=sig(gB)=f ; half1: v0=tanh(gA)=g, v1=sig(gB)=o
    const float v0 = fsig(gA * gmul) * gmul - (gmul - 1.f);
    const float v1 = fsig(gB);
    const float p0 = dpp_xor2_f(v0);                 // partner half's v0
    const float p1 = dpp_xor2_f(v1);
    const float iv = half ? p0 : v0;
    const float fv = half ? p1 : v1;
    const float gv = half ? v0 : p0;
    const float ov = half ? v1 : p1;

    c_st = fv * c_st + iv * gv;
    const float hv = ov * (2.f * fsig(2.f * c_st) - 1.f);

    if (write_h) {
      *hp = hv;
      hbuf[(s + 1) & 1][u] = (uint8_t)(int)rintf(hv * 127.f);  // |hv|<1
    }
    pp += pstep;
    hp += hstep;
    __syncthreads();
  }
}

// ---------------- 3. FUSED tail: feats (1024-thread wide) + CRF 12x12 fold -----------
// Phase 1: 1024 threads compute this chunk's 128x12 feats (1536 dots of length 512)
// into LDS fe + global feats (gold score needs it).  Phase 2: threads 0..191 fold
// the 128 steps into a 12x12 log-semiring matrix (identical math to k_crf_chunk).
// R8's version regressed because feats ran on 192 threads; 1024 fixes that while
// still saving the k_feats launch + the global feats round-trip into the fold.
__global__ __launch_bounds__(1024) void k_tail(const float* __restrict__ hs,
                                               const float* __restrict__ W_out,
                                               const float* __restrict__ b_out,
                                               const float* __restrict__ trans,
                                               float* __restrict__ feats,
                                               float* __restrict__ Pc) {
  const int ch  = blockIdx.x;
  const int tid = threadIdx.x;

  __shared__ float Wl[12 * 520];
  __shared__ float fe[CLEN * NTAGS];
  for (int i = tid; i < 12 * 512; i += 1024) Wl[(i / 512) * 520 + (i % 512)] = W_out[i];
  __syncthreads();

  for (int idx = tid; idx < CLEN * NTAGS; idx += 1024) {
    const int tl = idx / 12, n = idx % 12;
    const int t  = ch * CLEN + tl;
    const float4* hf4 = (const float4*)(hs + (long)t * HHD);
    const float4* hb4 = (const float4*)(hs + (long)SEQ * HHD + (long)t * HHD);
    const float4* Wa  = (const float4*)&Wl[n * 520];
    const float4* Wb  = (const float4*)&Wl[n * 520 + 256];
    float acc = b_out[n];
#pragma unroll 8
    for (int j = 0; j < 64; j++) {
      float4 w = Wa[j], h = hf4[j];
      acc += w.x * h.x + w.y * h.y + w.z * h.z + w.w * h.w;
    }
#pragma unroll 8
    for (int j = 0; j < 64; j++) {
      float4 w = Wb[j], h = hb4[j];
      acc += w.x * h.x + w.y * h.y + w.z * h.z + w.w * h.w;
    }
    fe[tl * NTAGS + n] = acc;
    feats[t * NTAGS + n] = acc;        // gold score (k_crf_final) reads this
  }
  __syncthreads();

  if (tid < 192) {
    const int n   = tid & 15;
    const int p   = tid >> 4;              // 0..11
    const int nn  = (n < 12) ? n : 11;

    float trn[12];
#pragma unroll
    for (int j = 0; j < 12; j++) trn[j] = trans[nn * 12 + j];

    float Mv = trn[p] + fe[nn];            // A_{t0}[n,p]
    for (int t = 1; t < CLEN; t++) {
      float x[12], m = -1e30f;
#pragma unroll
      for (int j = 0; j < 12; j++) {
        x[j] = trn[j] + __shfl(Mv, (tid & 48) | j, 64);
        m = fmaxf(m, x[j]);
      }
      float ss = 0.f;
#pragma unroll
      for (int j = 0; j < 12; j++) ss += __expf(x[j] - m);
      Mv = fe[t * NTAGS + nn] + m + __logf(ss);
    }
    if (n < 12) Pc[ch * 144 + n * 12 + p] = Mv;
  }
}

// ---------------- 4. combine chunk matrices + stop + gold score ----------------------
__global__ __launch_bounds__(128) void k_crf_final(const float* __restrict__ Pc,
                                                   const float* __restrict__ feats,
                                                   const int* __restrict__ tags,
                                                   const float* __restrict__ trans,
                                                   float* __restrict__ out) {
  __shared__ float Pl[CCH * 144];
  __shared__ float res[2];
  const int tid = threadIdx.x;
  for (int i = tid; i < CCH * 144; i += 128) Pl[i] = Pc[i];
  __syncthreads();

  if (tid < 64) {
    const int n  = tid;
    const int nn = (n < 12) ? n : 11;
    float fv = (n == START) ? 0.f : -10000.f;
    for (int c = 0; c < CCH; c++) {
      float x[12], m = -1e30f;
#pragma unroll
      for (int j = 0; j < 12; j++) {
        x[j] = Pl[c * 144 + nn * 12 + j] + __shfl(fv, j, 64);
        m = fmaxf(m, x[j]);
      }
      float ss = 0.f;
#pragma unroll
      for (int j = 0; j < 12; j++) ss += __expf(x[j] - m);
      fv = m + __logf(ss);
    }
    const float v = fv + trans[STOP * 12 + nn];
    float xs[12], m = -1e30f;
#pragma unroll
    for (int j = 0; j < 12; j++) {
      xs[j] = __shfl(v, j, 64);
      m = fmaxf(m, xs[j]);
    }
    float ss = 0.f;
#pragma unroll
    for (int j = 0; j < 12; j++) ss += __expf(xs[j] - m);
    if (tid == 0) res[0] = m + __logf(ss);
  } else {
    const int i = tid - 64;
    float gp = 0.f;
    for (int b = 0; b < 32; b++) {
      int t  = b * 64 + i;
      int tg = tags[t];
      int pv = (t == 0) ? START : tags[t - 1];
      gp += trans[tg * 12 + pv] + feats[t * NTAGS + tg];
    }
#pragma unroll
    for (int off = 32; off; off >>= 1) gp += __shfl_xor(gp, off, 64);
    if (i == 0) res[1] = gp + trans[STOP * 12 + tags[SEQ - 1]];
  }
  __syncthreads();
  if (tid == 0) out[0] = res[0] - res[1];
}

// -------------------------------------------------------------------------------------
extern "C" void kernel_launch(void* const* d_in, const int* in_sizes, int n_in,
                              void* d_out, int out_size, void* d_ws, size_t ws_size,
                              hipStream_t stream) {
  const int*   sentence = (const int*)  d_in[0];
  const int*   tags     = (const int*)  d_in[1];
  const float* embed    = (const float*)d_in[2];
  const float* Wih_f    = (const float*)d_in[3];
  const float* Whh_f    = (const float*)d_in[4];
  const float* bih_f    = (const float*)d_in[5];
  const float* bhh_f    = (const float*)d_in[6];
  const float* Wih_b    = (const float*)d_in[7];
  const float* Whh_b    = (const float*)d_in[8];
  const float* bih_b    = (const float*)d_in[9];
  const float* bhh_b    = (const float*)d_in[10];
  const float* W_out    = (const float*)d_in[11];
  const float* b_out    = (const float*)d_in[12];
  const float* h0       = (const float*)d_in[13];
  const float* c0       = (const float*)d_in[14];
  const float* trans    = (const float*)d_in[15];
  float* out = (float*)d_out;

  char* ws = (char*)d_ws;
  uint32_t* q4    = (uint32_t*)ws;                          // 512 KB
  float*    scales= (float*)(ws + (512l << 10));            // 8 KB
  float*    pre   = (float*)(ws + (1l  << 20));             // 16 MB : pre[2][2048][256][4]
  float*    hs    = (float*)(ws + (17l << 20));             // 4 MB  : hs[2][2048][256]
  float*    feats = (float*)(ws + (21l << 20));             // 96 KB : feats[2048][12]
  float*    Pc    = (float*)(ws + (21l << 20) + (128l<<10));// 9 KB  : Pc[16][12][12]

  k_front<<<1024, 256, 0, stream>>>(Whh_f, Whh_b, q4, scales,
                                    sentence, embed, Wih_f, bih_f, bhh_f,
                                    Wih_b, bih_b, bhh_b, pre);
  k_lstm<<<2, 512, 0, stream>>>(q4, scales, pre, h0, c0, hs);
  k_tail<<<CCH, 1024, 0, stream>>>(hs, W_out, b_out, trans, feats, Pc);
  k_crf_final<<<1, 128, 0, stream>>>(Pc, feats, tags, trans, out);
}

// Round 11
// 1795.791 us; speedup vs baseline: 2.3172x; 1.0015x over previous
//
#include <hip/hip_runtime.h>
#include <hip/hip_bf16.h>
#include <stdint.h>

#define SEQ   2048
#define EMB   256
#define HHD   256      // per-direction hidden
#define GATES 1024     // 4*HHD
#define NTAGS 12
#define START 10
#define STOP  11
#define CCH   16       // CRF chunks
#define CLEN  128      // steps per chunk

__device__ __forceinline__ int sdot4(uint32_t a, uint32_t b, int c) {
#if __has_builtin(__builtin_amdgcn_sdot4)
  return __builtin_amdgcn_sdot4((int)a, (int)b, c, false);
#else
  int r = c;
#pragma unroll
  for (int i = 0; i < 4; i++) {
    int av = (int)(signed char)((a >> (8 * i)) & 255);
    int bv = (int)(signed char)((b >> (8 * i)) & 255);
    r += av * bv;
  }
  return r;
#endif
}

__device__ __forceinline__ float fsig(float x) {
  float e = __expf(-x);
  return __builtin_amdgcn_rcpf(1.0f + e);
}

// DPP quad_perm lane swaps (stay on VALU pipe, no LDS)
__device__ __forceinline__ int dpp_xor1(int x) {   // lanes q <-> q^1 : [1,0,3,2]
  return __builtin_amdgcn_update_dpp(0, x, 0xB1, 0xF, 0xF, true);
}
__device__ __forceinline__ int dpp_xor2(int x) {   // lanes q <-> q^2 : [2,3,0,1]
  return __builtin_amdgcn_update_dpp(0, x, 0x4E, 0xF, 0xF, true);
}
__device__ __forceinline__ float dpp_xor2_f(float x) {
  int r = __builtin_amdgcn_update_dpp(0, __float_as_int(x), 0x4E, 0xF, 0xF, true);
  return __int_as_float(r);
}

// ---------------- 1. FUSED front end: quant (blocks 0..511) + proj (512..1023) -------
// quant: Whh fp32 -> int8 rows with per-row scale (one wave per row).
// proj : pre[dir][t][unit][{i,f,g,o}] = bih+bhh + Wih @ embed[sent[t]], thread-per-
// unit, j-outer/kq-inner (streamed W rows, L1-resident), coalesced float4 stores.
// Also zeroes the k_tail completion counter (stream order guarantees visibility).
__global__ __launch_bounds__(256) void k_front(const float* __restrict__ whh_f,
                                               const float* __restrict__ whh_b,
                                               uint32_t* __restrict__ q4,
                                               float* __restrict__ scales,
                                               const int* __restrict__ sentence,
                                               const float* __restrict__ embed,
                                               const float* __restrict__ Wih_f,
                                               const float* __restrict__ bih_f,
                                               const float* __restrict__ bhh_f,
                                               const float* __restrict__ Wih_b,
                                               const float* __restrict__ bih_b,
                                               const float* __restrict__ bhh_b,
                                               float* __restrict__ pre,
                                               unsigned int* __restrict__ cnt) {
  if (blockIdx.x == 0 && threadIdx.x == 0) *cnt = 0;   // reset last-block counter
  if (blockIdx.x < 512) {
    // ---------------- quant ----------------
    const int row  = (blockIdx.x * 256 + threadIdx.x) >> 6;  // 0..2047
    const int lane = threadIdx.x & 63;
    const int d = row >> 10, r = row & 1023;
    const float4 w = *(const float4*)((d ? whh_b : whh_f) + (long)r * HHD + lane * 4);
    float m = fmaxf(fmaxf(fabsf(w.x), fabsf(w.y)), fmaxf(fabsf(w.z), fabsf(w.w)));
#pragma unroll
    for (int off = 32; off; off >>= 1) m = fmaxf(m, __shfl_xor(m, off, 64));
    m = fmaxf(m, 1e-20f);
    const float inv = 127.f / m;
    int a = (int)rintf(w.x * inv), b = (int)rintf(w.y * inv);
    int c = (int)rintf(w.z * inv), e = (int)rintf(w.w * inv);
    q4[row * 64 + lane] = (uint32_t)(a & 255) | ((uint32_t)(b & 255) << 8) |
                          ((uint32_t)(c & 255) << 16) | ((uint32_t)(e & 255) << 24);
    if (lane == 0) scales[row] = m / 127.f;
    return;
  }
  // ---------------- proj (thread-per-unit, j-outer) ----------------
  const int bid2 = blockIdx.x - 512;      // 0..511
  const int dir  = bid2 >> 8;             // 0..1
  const int t0   = (bid2 & 255) * 8;
  const float* Wih = dir ? Wih_b : Wih_f;
  const float* bih = dir ? bih_b : bih_f;
  const float* bhh = dir ? bhh_b : bhh_f;

  __shared__ float xs[8][256];
  const int uu = threadIdx.x;             // unit 0..255
#pragma unroll
  for (int i = 0; i < 8; i++) {
    int s = sentence[t0 + i];
    xs[i][uu] = embed[(long)s * EMB + uu];
  }
  __syncthreads();

  float acc[4][8];                        // [gate][t]
#pragma unroll
  for (int j = 0; j < 4; j++)
#pragma unroll
    for (int t = 0; t < 8; t++) acc[j][t] = 0.f;

  const float4* W4 = (const float4*)Wih;
#pragma unroll
  for (int j = 0; j < 4; j++) {
    const float4* Wrow = W4 + (long)(j * 256 + uu) * 64;   // this thread's row j
    for (int kq = 0; kq < 64; kq++) {
      const float4 w = Wrow[kq];                           // streamed, L1-resident
#pragma unroll
      for (int t = 0; t < 8; t++) {
        const float4 xv = ((const float4*)xs[t])[kq];
        acc[j][t] += w.x * xv.x + w.y * xv.y + w.z * xv.z + w.w * xv.w;
      }
    }
  }
  float bs[4];
#pragma unroll
  for (int j = 0; j < 4; j++) bs[j] = bih[j * 256 + uu] + bhh[j * 256 + uu];
#pragma unroll
  for (int t = 0; t < 8; t++) {
    float4 o = {acc[0][t] + bs[0], acc[1][t] + bs[1],
                acc[2][t] + bs[2], acc[3][t] + bs[3]};
    *(float4*)&pre[(((long)(dir * SEQ + t0 + t)) * HHD + uu) * 4] = o;  // coalesced
  }
}

// ---------------- 2. sequential LSTM: K-split quads + DPP reduction (R1, best) ------
// Lane L: q = L&3 (K-quarter), g = L>>2 (unit pair 2g,2g+1), p = q&1 (unit parity),
// half = q>>1 (0: gates i,f ; 1: gates g,o).  Slot j holds rows for lane q^j so a
// 2-level DPP quad butterfly lands each lane's own 2 gate sums in slot 0.
// h kept as int8 in LDS (|h|<1 -> fixed scale 1/127), double-buffered, 1 barrier/step.
__global__ __launch_bounds__(512, 2) void k_lstm(const uint32_t* __restrict__ q4,
                                                 const float* __restrict__ scales,
                                                 const float* __restrict__ pre,
                                                 const float* __restrict__ h0,
                                                 const float* __restrict__ c0,
                                                 float* __restrict__ hs) {
  const int dir  = blockIdx.x;
  const int L    = threadIdx.x;
  const int q    = L & 3;
  const int g    = L >> 2;       // 0..127
  const int p    = q & 1;
  const int half = q >> 1;
  const int u    = 2 * g + p;

  __shared__ __align__(16) uint8_t hbuf[2][256];

  const long base = (long)dir * GATES;

  uint4 wa[4][4], wb[4][4];
  const uint4* qq = (const uint4*)q4;
#pragma unroll
  for (int j = 0; j < 4; j++) {
    const int qj = q ^ j;
    const int rA = (2 * (qj >> 1)) * 256 + 2 * g + (qj & 1);
    const int rB = rA + 256;
#pragma unroll
    for (int k = 0; k < 4; k++) {
      wa[j][k] = qq[(base + rA) * 16 + 4 * q + k];   // own K-quarter q
      wb[j][k] = qq[(base + rB) * 16 + 4 * q + k];
    }
  }
  const int rown = (2 * half) * 256 + u;             // own A row (gate 2*half)
  const float sA = scales[base + rown];
  const float sB = scales[base + rown + 256];

  // seed h buffer 0 from h0 (scale 4/127: h0 ~ N(0,1), clamp at |4|)
  if (L < 256) {
    float v = h0[dir * HHD + L] * (127.f / 4.f);
    v = fminf(fmaxf(v, -127.f), 127.f);
    hbuf[0][L] = (uint8_t)(int)rintf(v);
  }
  float c_st = c0[dir * HHD + u];
  __syncthreads();

  const int t0 = dir ? (SEQ - 1) : 0;
  const long pstep = dir ? -(long)(HHD * 4) : (long)(HHD * 4);
  const long hstep = dir ? -(long)HHD : (long)HHD;
  const float* pp = pre + (long)dir * SEQ * (HHD * 4) + ((long)t0 * HHD + u) * 4 + 2 * half;
  float* hp       = hs  + (long)dir * SEQ * HHD + (long)t0 * HHD + u;
  const float gmul = half ? 2.f : 1.f;   // tanh(x) = 2*sig(2x)-1 trick, divergence-free
  const int write_h = ((L & 2) == 0);

  for (int s = 0; s < SEQ; s++) {
    const float2 pr = *(const float2*)pp;            // my 2 gate pre-activations

    const uint4* hq4 = (const uint4*)(hbuf[s & 1] + (q << 6));
    const uint4 h0v = hq4[0], h1v = hq4[1], h2v = hq4[2], h3v = hq4[3];

    int pa0 = 0, pa1 = 0, pa2 = 0, pa3 = 0;
    int pb0 = 0, pb1 = 0, pb2 = 0, pb3 = 0;
#pragma unroll
    for (int k = 0; k < 4; k++) {
      const uint4 hk = (k == 0) ? h0v : (k == 1) ? h1v : (k == 2) ? h2v : h3v;
      pa0 = sdot4(wa[0][k].x, hk.x, pa0); pa0 = sdot4(wa[0][k].y, hk.y, pa0);
      pa0 = sdot4(wa[0][k].z, hk.z, pa0); pa0 = sdot4(wa[0][k].w, hk.w, pa0);
      pa1 = sdot4(wa[1][k].x, hk.x, pa1); pa1 = sdot4(wa[1][k].y, hk.y, pa1);
      pa1 = sdot4(wa[1][k].z, hk.z, pa1); pa1 = sdot4(wa[1][k].w, hk.w, pa1);
      pa2 = sdot4(wa[2][k].x, hk.x, pa2); pa2 = sdot4(wa[2][k].y, hk.y, pa2);
      pa2 = sdot4(wa[2][k].z, hk.z, pa2); pa2 = sdot4(wa[2][k].w, hk.w, pa2);
      pa3 = sdot4(wa[3][k].x, hk.x, pa3); pa3 = sdot4(wa[3][k].y, hk.y, pa3);
      pa3 = sdot4(wa[3][k].z, hk.z, pa3); pa3 = sdot4(wa[3][k].w, hk.w, pa3);
      pb0 = sdot4(wb[0][k].x, hk.x, pb0); pb0 = sdot4(wb[0][k].y, hk.y, pb0);
      pb0 = sdot4(wb[0][k].z, hk.z, pb0); pb0 = sdot4(wb[0][k].w, hk.w, pb0);
      pb1 = sdot4(wb[1][k].x, hk.x, pb1); pb1 = sdot4(wb[1][k].y, hk.y, pb1);
      pb1 = sdot4(wb[1][k].z, hk.z, pb1); pb1 = sdot4(wb[1][k].w, hk.w, pb1);
      pb2 = sdot4(wb[2][k].x, hk.x, pb2); pb2 = sdot4(wb[2][k].y, hk.y, pb2);
      pb2 = sdot4(wb[2][k].z, hk.z, pb2); pb2 = sdot4(wb[2][k].w, hk.w, pb2);
      pb3 = sdot4(wb[3][k].x, hk.x, pb3); pb3 = sdot4(wb[3][k].y, hk.y, pb3);
      pb3 = sdot4(wb[3][k].z, hk.z, pb3); pb3 = sdot4(wb[3][k].w, hk.w, pb3);
    }
    // 2-level quad butterfly: slot0 of each lane ends with its own full row sums
    const int tA = pa0 + dpp_xor1(pa1);
    const int tA2 = pa2 + dpp_xor1(pa3);
    const int sumA = tA + dpp_xor2(tA2);
    const int tB = pb0 + dpp_xor1(pb1);
    const int tB2 = pb2 + dpp_xor1(pb3);
    const int sumB = tB + dpp_xor2(tB2);

    const float hsc = (s == 0) ? (4.f / 127.f) : (1.f / 127.f);
    const float gA = pr.x + sA * hsc * (float)sumA;  // i (even) | g (odd)
    const float gB = pr.y + sB * hsc * (float)sumB;  // f (even) | o (odd)

    // half0: v0=sig(gA)=i, v1=sig(gB)=f ; half1: v0=tanh(gA)=g, v1=sig(gB)=o
    const float v0 = fsig(gA * gmul) * gmul - (gmul - 1.f);
    const float v1 = fsig(gB);
    const float p0 = dpp_xor2_f(v0);                 // partner half's v0
    const float p1 = dpp_xor2_f(v1);
    const float iv = half ? p0 : v0;
    const float fv = half ? p1 : v1;
    const float gv = half ? v0 : p0;
    const float ov = half ? v1 : p1;

    c_st = fv * c_st + iv * gv;
    const float hv = ov * (2.f * fsig(2.f * c_st) - 1.f);

    if (write_h) {
      *hp = hv;
      hbuf[(s + 1) & 1][u] = (uint8_t)(int)rintf(hv * 127.f);  // |hv|<1
    }
    pp += pstep;
    hp += hstep;
    __syncthreads();
  }
}

// ---------------- 3. FUSED tail: feats + CRF fold + gold + last-block final ----------
// Per chunk block (1024 thr): phase 1 computes the chunk's 128x12 feats into LDS fe
// (wide, 1024 threads).  Phase 2: waves 0-2 (tid<192) fold the 128 steps into a
// 12x12 log-semiring matrix -> Pc[ch]; waves 4-5 (tid 256..383) compute the chunk's
// gold-score slice from fe -> Gc[ch] (global feats array eliminated).  Then
// __threadfence + device-scope counter increment; the LAST block to finish loads
// all Pc/Gc and produces out[0] in-kernel (k_crf_final launch eliminated).
__global__ __launch_bounds__(1024) void k_tail(const float* __restrict__ hs,
                                               const float* __restrict__ W_out,
                                               const float* __restrict__ b_out,
                                               const float* __restrict__ trans,
                                               const int* __restrict__ tags,
                                               float* __restrict__ Pc,
                                               float* __restrict__ Gc,
                                               unsigned int* __restrict__ cnt,
                                               float* __restrict__ out) {
  const int ch  = blockIdx.x;
  const int tid = threadIdx.x;

  __shared__ float Wl[12 * 520];
  __shared__ float fe[CLEN * NTAGS];
  __shared__ float gpart[2];
  __shared__ int   sh_last;
  for (int i = tid; i < 12 * 512; i += 1024) Wl[(i / 512) * 520 + (i % 512)] = W_out[i];
  __syncthreads();

  // ---- phase 1: feats (wide) ----
  for (int idx = tid; idx < CLEN * NTAGS; idx += 1024) {
    const int tl = idx / 12, n = idx % 12;
    const int t  = ch * CLEN + tl;
    const float4* hf4 = (const float4*)(hs + (long)t * HHD);
    const float4* hb4 = (const float4*)(hs + (long)SEQ * HHD + (long)t * HHD);
    const float4* Wa  = (const float4*)&Wl[n * 520];
    const float4* Wb  = (const float4*)&Wl[n * 520 + 256];
    float acc = b_out[n];
#pragma unroll 8
    for (int j = 0; j < 64; j++) {
      float4 w = Wa[j], h = hf4[j];
      acc += w.x * h.x + w.y * h.y + w.z * h.z + w.w * h.w;
    }
#pragma unroll 8
    for (int j = 0; j < 64; j++) {
      float4 w = Wb[j], h = hb4[j];
      acc += w.x * h.x + w.y * h.y + w.z * h.z + w.w * h.w;
    }
    fe[tl * NTAGS + n] = acc;
  }
  __syncthreads();

  // ---- phase 2a: CRF fold (waves 0-2) ----
  if (tid < 192) {
    const int n   = tid & 15;
    const int p   = tid >> 4;              // 0..11
    const int nn  = (n < 12) ? n : 11;

    float trn[12];
#pragma unroll
    for (int j = 0; j < 12; j++) trn[j] = trans[nn * 12 + j];

    float Mv = trn[p] + fe[nn];            // A_{t0}[n,p]
    for (int t = 1; t < CLEN; t++) {
      float x[12], m = -1e30f;
#pragma unroll
      for (int j = 0; j < 12; j++) {
        x[j] = trn[j] + __shfl(Mv, (tid & 48) | j, 64);
        m = fmaxf(m, x[j]);
      }
      float ss = 0.f;
#pragma unroll
      for (int j = 0; j < 12; j++) ss += __expf(x[j] - m);
      Mv = fe[t * NTAGS + nn] + m + __logf(ss);
    }
    if (n < 12) Pc[ch * 144 + n * 12 + p] = Mv;
  }
  // ---- phase 2b: gold-score slice (waves 4-5, parallel to the fold) ----
  else if (tid >= 256 && tid < 384) {
    const int tl = tid - 256;              // 0..127
    const int t  = ch * CLEN + tl;
    const int tg = tags[t];
    const int pv = (t == 0) ? START : tags[t - 1];
    float gv = trans[tg * 12 + pv] + fe[tl * NTAGS + tg];
#pragma unroll
    for (int off = 32; off; off >>= 1) gv += __shfl_xor(gv, off, 64);
    if ((tid & 63) == 0) gpart[(tid >> 6) - 4] = gv;
  }
  __syncthreads();

  if (tid == 0) {
    float gc = gpart[0] + gpart[1];
    if (ch == CCH - 1) gc += trans[STOP * 12 + tags[SEQ - 1]];
    Gc[ch] = gc;
    __threadfence();                       // make Pc/Gc visible device-wide
    unsigned int old = __hip_atomic_fetch_add(cnt, 1u, __ATOMIC_ACQ_REL,
                                              __HIP_MEMORY_SCOPE_AGENT);
    sh_last = (old == CCH - 1);
  }
  __syncthreads();

  // ---- last block: final combine (replaces k_crf_final) ----
  if (sh_last) {
    __shared__ float Pl[CCH * 144];
    __shared__ float res[2];
    for (int i = tid; i < CCH * 144; i += 1024) Pl[i] = Pc[i];
    if (tid == 64) {
      float gs = 0.f;
#pragma unroll
      for (int c = 0; c < CCH; c++) gs += Gc[c];
      res[1] = gs;
    }
    __syncthreads();
    if (tid < 64) {
      const int n  = tid;
      const int nn = (n < 12) ? n : 11;
      float fv = (n == START) ? 0.f : -10000.f;
      for (int c = 0; c < CCH; c++) {
        float x[12], m = -1e30f;
#pragma unroll
        for (int j = 0; j < 12; j++) {
          x[j] = Pl[c * 144 + nn * 12 + j] + __shfl(fv, j, 64);
          m = fmaxf(m, x[j]);
        }
        float ss = 0.f;
#pragma unroll
        for (int j = 0; j < 12; j++) ss += __expf(x[j] - m);
        fv = m + __logf(ss);
      }
      const float v = fv + trans[STOP * 12 + nn];
      float xs[12], m = -1e30f;
#pragma unroll
      for (int j = 0; j < 12; j++) {
        xs[j] = __shfl(v, j, 64);
        m = fmaxf(m, xs[j]);
      }
      float ss = 0.f;
#pragma unroll
      for (int j = 0; j < 12; j++) ss += __expf(xs[j] - m);
      if (tid == 0) out[0] = (m + __logf(ss)) - res[1];
    }
  }
}

// -------------------------------------------------------------------------------------
extern "C" void kernel_launch(void* const* d_in, const int* in_sizes, int n_in,
                              void* d_out, int out_size, void* d_ws, size_t ws_size,
                              hipStream_t stream) {
  const int*   sentence = (const int*)  d_in[0];
  const int*   tags     = (const int*)  d_in[1];
  const float* embed    = (const float*)d_in[2];
  const float* Wih_f    = (const float*)d_in[3];
  const float* Whh_f    = (const float*)d_in[4];
  const float* bih_f    = (const float*)d_in[5];
  const float* bhh_f    = (const float*)d_in[6];
  const float* Wih_b    = (const float*)d_in[7];
  const float* Whh_b    = (const float*)d_in[8];
  const float* bih_b    = (const float*)d_in[9];
  const float* bhh_b    = (const float*)d_in[10];
  const float* W_out    = (const float*)d_in[11];
  const float* b_out    = (const float*)d_in[12];
  const float* h0       = (const float*)d_in[13];
  const float* c0       = (const float*)d_in[14];
  const float* trans    = (const float*)d_in[15];
  float* out = (float*)d_out;

  char* ws = (char*)d_ws;
  uint32_t* q4    = (uint32_t*)ws;                          // 512 KB
  float*    scales= (float*)(ws + (512l << 10));            // 8 KB
  float*    pre   = (float*)(ws + (1l  << 20));             // 16 MB : pre[2][2048][256][4]
  float*    hs    = (float*)(ws + (17l << 20));             // 4 MB  : hs[2][2048][256]
  float*    Pc    = (float*)(ws + (21l << 20));             // 9 KB  : Pc[16][12][12]
  float*    Gc    = (float*)(ws + (21l << 20) + (16l<<10)); // 64 B  : Gc[16]
  unsigned* cnt   = (unsigned*)(ws + (21l << 20) + (32l<<10)); // 4 B : completion ctr

  k_front<<<1024, 256, 0, stream>>>(Whh_f, Whh_b, q4, scales,
                                    sentence, embed, Wih_f, bih_f, bhh_f,
                                    Wih_b, bih_b, bhh_b, pre, cnt);
  k_lstm<<<2, 512, 0, stream>>>(q4, scales, pre, h0, c0, hs);
  k_tail<<<CCH, 1024, 0, stream>>>(hs, W_out, b_out, trans, tags, Pc, Gc, cnt, out);
}